// Round 6
// baseline (1429.324 us; speedup 1.0000x reference)
//
#include <hip/hip_runtime.h>
#include <math.h>

#define HD 128
#define GG 64
#define CSB 64    // colstat partial slots (per layer)
#define PSL 8     // pooled partial slots

typedef __attribute__((ext_vector_type(8))) short short8;
typedef __attribute__((ext_vector_type(4))) float f32x4;
typedef __attribute__((ext_vector_type(2))) float f32x2;

__device__ __forceinline__ float leaky(float x, float s) { return x > 0.f ? x : s * x; }

__device__ __forceinline__ unsigned short bf16_of(float f) {
    union { float f; unsigned u; } v; v.f = f;
    unsigned r = v.u + 0x7fffu + ((v.u >> 16) & 1u);
    return (unsigned short)(r >> 16);
}
__device__ __forceinline__ float f_of_bf16(unsigned short u) {
    union { unsigned u; float f; } v; v.u = ((unsigned)u) << 16;
    return v.f;
}

// XOR-swizzled LDS addressing for the 128x128 bf16 W tile (16B chunks).
__device__ __forceinline__ int sw(int row, int chunk) {
    return row * 128 + ((chunk ^ (row & 15)) << 3);
}

// -------- init: W->Wt bf16 transposed + zero bucket counters / part / pooled / ctr --
__global__ void k_init(const float* __restrict__ Ws, unsigned short* __restrict__ Wt,
                       int* __restrict__ bcnt, float* __restrict__ part,
                       float* __restrict__ pooled, int* __restrict__ ctr) {
    int i = blockIdx.x * 256 + threadIdx.x;   // grid 512*256 = 131072
    if (i < 3 * 16384) {
        int l = i >> 14, rem = i & 16383;
        int nn = rem >> 7, k = rem & 127;
        Wt[i] = bf16_of(Ws[l * 16384 + k * 128 + nn]);
    }
    if (i < 513) bcnt[i] = 0;
    if (i < 2) ctr[i] = 0;
    if (i < 2 * CSB * 256) part[i] = 0.f;     // 32768
    if (i < PSL * GG * HD) pooled[i] = 0.f;   // 65536
}

// ================= register-A + LDS-B MFMA GEMM, 64-row blocks =============
// (round-1 form: mfma(af, bfr); per-reg epilogue with 16-lane shuffle att dots)

// ---- variant A: fp32 input (layer 0, no norm) ----
__global__ __launch_bounds__(256) void k_gemm_a32(
    const float* __restrict__ A, const unsigned short* __restrict__ Wt,
    const float* __restrict__ att_s, const float* __restrict__ att_d,
    unsigned short* __restrict__ hWb, float* __restrict__ a_s, float* __restrict__ a_d,
    int n) {
    __shared__ unsigned short Bs[128 * 128];
    const int tid = threadIdx.x;
    const int base = blockIdx.x * 64;

    const uint4* Wt4 = (const uint4*)Wt;
    uint4* Bs4 = (uint4*)Bs;
#pragma unroll
    for (int j = 0; j < 8; ++j) {
        int flat = tid + j * 256;
        int col = flat >> 4, c8 = flat & 15;
        Bs4[(col << 4) + (c8 ^ (col & 15))] = Wt4[flat];
    }

    const int wave = tid >> 6, lane = tid & 63;
    const int m16 = lane & 15, quad = lane >> 4;

    short8 af[4];
    {
        int row = base + wave * 16 + m16;
        row = (row < n) ? row : (n - 1);
        const float4* ap = (const float4*)(A + (size_t)row * 128);
#pragma unroll
        for (int kk = 0; kk < 4; ++kk) {
            float4 v0 = ap[kk * 8 + quad * 2];
            float4 v1 = ap[kk * 8 + quad * 2 + 1];
            union { short8 s; unsigned u[4]; } P;
            P.u[0] = (unsigned)bf16_of(v0.x) | ((unsigned)bf16_of(v0.y) << 16);
            P.u[1] = (unsigned)bf16_of(v0.z) | ((unsigned)bf16_of(v0.w) << 16);
            P.u[2] = (unsigned)bf16_of(v1.x) | ((unsigned)bf16_of(v1.y) << 16);
            P.u[3] = (unsigned)bf16_of(v1.z) | ((unsigned)bf16_of(v1.w) << 16);
            af[kk] = P.s;
        }
    }
    __syncthreads();

    f32x4 acc[8];
#pragma unroll
    for (int ct = 0; ct < 8; ++ct) acc[ct] = (f32x4){0.f, 0.f, 0.f, 0.f};
#pragma unroll
    for (int kk = 0; kk < 4; ++kk) {
#pragma unroll
        for (int ct = 0; ct < 8; ++ct) {
            short8 bfr = *(const short8*)&Bs[sw(ct * 16 + m16, kk * 4 + quad)];
            acc[ct] = __builtin_amdgcn_mfma_f32_16x16x32_bf16(af[kk], bfr, acc[ct], 0, 0, 0);
        }
    }

#pragma unroll
    for (int reg = 0; reg < 4; ++reg) {
        int gr = base + wave * 16 + quad * 4 + reg;
        bool ok = gr < n;
        unsigned short* rowp = hWb + (size_t)gr * 128 + m16;
        float s = 0.f, dd = 0.f;
#pragma unroll
        for (int ct = 0; ct < 8; ++ct) {
            float v = acc[ct][reg];
            int col = ct * 16 + m16;
            if (ok) rowp[ct * 16] = bf16_of(v);
            s = fmaf(v, att_s[col], s);
            dd = fmaf(v, att_d[col], dd);
        }
#pragma unroll
        for (int off = 1; off < 16; off <<= 1) {
            s += __shfl_xor(s, off, 64);
            dd += __shfl_xor(dd, off, 64);
        }
        if (m16 == 0 && ok) { a_s[gr] = s; a_d[gr] = dd; }
    }
}

// ---- variant B: bf16 input + GraphNorm affine + leaky (layers 1,2) ----
__global__ __launch_bounds__(256) void k_gemm_a16(
    const unsigned short* __restrict__ Ab, const unsigned short* __restrict__ Wt,
    const float* __restrict__ att_s, const float* __restrict__ att_d,
    const float* __restrict__ alpha, const float* __restrict__ beta,
    unsigned short* __restrict__ hWb, float* __restrict__ a_s, float* __restrict__ a_d,
    int n) {
    __shared__ unsigned short Bs[128 * 128];
    const int tid = threadIdx.x;
    const int base = blockIdx.x * 64;

    const uint4* Wt4 = (const uint4*)Wt;
    uint4* Bs4 = (uint4*)Bs;
#pragma unroll
    for (int j = 0; j < 8; ++j) {
        int flat = tid + j * 256;
        int col = flat >> 4, c8 = flat & 15;
        Bs4[(col << 4) + (c8 ^ (col & 15))] = Wt4[flat];
    }

    const int wave = tid >> 6, lane = tid & 63;
    const int m16 = lane & 15, quad = lane >> 4;
    const float4* al4 = (const float4*)alpha;
    const float4* be4 = (const float4*)beta;

    short8 af[4];
    {
        int row = base + wave * 16 + m16;
        row = (row < n) ? row : (n - 1);
        const uint4* ap = (const uint4*)(Ab + (size_t)row * 128);
#pragma unroll
        for (int kk = 0; kk < 4; ++kk) {
            uint4 raw = ap[kk * 4 + quad];
            int c4 = kk * 8 + quad * 2;
            float4 a0 = al4[c4], a1 = al4[c4 + 1];
            float4 b0 = be4[c4], b1 = be4[c4 + 1];
            float f0 = leaky(fmaf(f_of_bf16(raw.x & 0xffff), a0.x, b0.x), 0.01f);
            float f1 = leaky(fmaf(f_of_bf16(raw.x >> 16),    a0.y, b0.y), 0.01f);
            float f2 = leaky(fmaf(f_of_bf16(raw.y & 0xffff), a0.z, b0.z), 0.01f);
            float f3 = leaky(fmaf(f_of_bf16(raw.y >> 16),    a0.w, b0.w), 0.01f);
            float f4 = leaky(fmaf(f_of_bf16(raw.z & 0xffff), a1.x, b1.x), 0.01f);
            float f5 = leaky(fmaf(f_of_bf16(raw.z >> 16),    a1.y, b1.y), 0.01f);
            float f6 = leaky(fmaf(f_of_bf16(raw.w & 0xffff), a1.z, b1.z), 0.01f);
            float f7 = leaky(fmaf(f_of_bf16(raw.w >> 16),    a1.w, b1.w), 0.01f);
            union { short8 s; unsigned u[4]; } P;
            P.u[0] = (unsigned)bf16_of(f0) | ((unsigned)bf16_of(f1) << 16);
            P.u[1] = (unsigned)bf16_of(f2) | ((unsigned)bf16_of(f3) << 16);
            P.u[2] = (unsigned)bf16_of(f4) | ((unsigned)bf16_of(f5) << 16);
            P.u[3] = (unsigned)bf16_of(f6) | ((unsigned)bf16_of(f7) << 16);
            af[kk] = P.s;
        }
    }
    __syncthreads();

    f32x4 acc[8];
#pragma unroll
    for (int ct = 0; ct < 8; ++ct) acc[ct] = (f32x4){0.f, 0.f, 0.f, 0.f};
#pragma unroll
    for (int kk = 0; kk < 4; ++kk) {
#pragma unroll
        for (int ct = 0; ct < 8; ++ct) {
            short8 bfr = *(const short8*)&Bs[sw(ct * 16 + m16, kk * 4 + quad)];
            acc[ct] = __builtin_amdgcn_mfma_f32_16x16x32_bf16(af[kk], bfr, acc[ct], 0, 0, 0);
        }
    }

#pragma unroll
    for (int reg = 0; reg < 4; ++reg) {
        int gr = base + wave * 16 + quad * 4 + reg;
        bool ok = gr < n;
        unsigned short* rowp = hWb + (size_t)gr * 128 + m16;
        float s = 0.f, dd = 0.f;
#pragma unroll
        for (int ct = 0; ct < 8; ++ct) {
            float v = acc[ct][reg];
            int col = ct * 16 + m16;
            if (ok) rowp[ct * 16] = bf16_of(v);
            s = fmaf(v, att_s[col], s);
            dd = fmaf(v, att_d[col], dd);
        }
#pragma unroll
        for (int off = 1; off < 16; off <<= 1) {
            s += __shfl_xor(s, off, 64);
            dd += __shfl_xor(dd, off, 64);
        }
        if (m16 == 0 && ok) { a_s[gr] = s; a_d[gr] = dd; }
    }
}

// ================= bucketed CSR build (LDS atomics, compact writes) =============
// Buckets of 512 nodes: bucket b = dst >> 9, local id = dst & 511.
// ebuf packs (local << 18) | src  (valid for n <= 262144).

__global__ __launch_bounds__(256) void k_bcount(const int* __restrict__ dst,
                                                int* __restrict__ bcnt, int e) {
    __shared__ int lh[512];
    const int tid = threadIdx.x;
    for (int t = tid; t < 512; t += 256) lh[t] = 0;
    __syncthreads();
    for (int i = blockIdx.x * 256 + tid; i < e; i += gridDim.x * 256)
        atomicAdd(&lh[dst[i] >> 9], 1);
    __syncthreads();
    for (int t = tid; t < 512; t += 256)
        if (lh[t]) atomicAdd(&bcnt[t], lh[t]);
}

__global__ void k_bscan(const int* __restrict__ bcnt, int* __restrict__ bbase,
                        int* __restrict__ bcur, int* __restrict__ offs,
                        int nbk, int n, int e) {
    __shared__ int s[512];
    int t = threadIdx.x;
    int v = (t < nbk) ? bcnt[t] : 0;
    s[t] = v;
    __syncthreads();
    for (int off = 1; off < 512; off <<= 1) {
        int u = (t >= off) ? s[t - off] : 0;
        __syncthreads();
        s[t] += u;
        __syncthreads();
    }
    if (t < nbk) { bbase[t] = s[t] - v; bcur[t] = s[t] - v; }
    if (t == 0) { bbase[nbk] = e; offs[n] = e; }
}

__global__ __launch_bounds__(256) void k_part(const int* __restrict__ src,
                                              const int* __restrict__ dst,
                                              int* __restrict__ bcur,
                                              int* __restrict__ ebuf, int e) {
    __shared__ int lh[512];
    __shared__ int lbase[512];
    const int tid = threadIdx.x;
    const int chunk = (e + gridDim.x - 1) / gridDim.x;
    const int i0 = blockIdx.x * chunk;
    const int i1 = min(e, i0 + chunk);
    for (int t = tid; t < 512; t += 256) lh[t] = 0;
    __syncthreads();
    for (int i = i0 + tid; i < i1; i += 256) atomicAdd(&lh[dst[i] >> 9], 1);
    __syncthreads();
    for (int t = tid; t < 512; t += 256) {
        int c = lh[t];
        lbase[t] = c ? atomicAdd(&bcur[t], c) : 0;
    }
    __syncthreads();
    for (int t = tid; t < 512; t += 256) lh[t] = 0;
    __syncthreads();
    for (int i = i0 + tid; i < i1; i += 256) {
        int d = dst[i];
        int b = d >> 9;
        int p = lbase[b] + atomicAdd(&lh[b], 1);
        ebuf[p] = ((d & 511) << 18) | src[i];
    }
}

__global__ __launch_bounds__(256) void k_bscatter(const int* __restrict__ ebuf,
                                                  const int* __restrict__ bbase,
                                                  int* __restrict__ offs,
                                                  int* __restrict__ esrc, int n) {
    const int b = blockIdx.x;
    const int tid = threadIdx.x;
    const int nb0 = b << 9;
    const int e0 = bbase[b], e1 = bbase[b + 1];
    __shared__ int cnt[512];
    __shared__ int sc[512];
    __shared__ int pos[512];
    for (int t = tid; t < 512; t += 256) cnt[t] = 0;
    __syncthreads();
    for (int i = e0 + tid; i < e1; i += 256) atomicAdd(&cnt[ebuf[i] >> 18], 1);
    __syncthreads();
    for (int t = tid; t < 512; t += 256) sc[t] = cnt[t];
    __syncthreads();
    for (int off = 1; off < 512; off <<= 1) {
        int t0 = tid, t1 = tid + 256;
        int v0 = (t0 >= off) ? sc[t0 - off] : 0;
        int v1 = sc[t1 - off];
        __syncthreads();
        sc[t0] += v0;
        sc[t1] += v1;
        __syncthreads();
    }
    for (int t = tid; t < 512; t += 256) pos[t] = e0 + sc[t] - cnt[t];
    __syncthreads();
    for (int t = tid; t < 512; t += 256) {
        int node = nb0 + t;
        if (node < n) offs[node] = pos[t];
    }
    __syncthreads();
    for (int i = e0 + tid; i < e1; i += 256) {
        int v = ebuf[i];
        int l = v >> 18;
        int p = atomicAdd(&pos[l], 1);
        esrc[p] = v & 0x3FFFF;
    }
}

// ---------------- fused attention softmax + aggregation -------------------
// One 16-lane group per destination node. Tails:
//   part != nullptr (layers 0,1): write bf16 h, GraphNorm stats block-reduce +
//     atomicAdd into part slot; LAST block (device counter) computes alpha/beta.
//   pooled != nullptr (layer 2): NO h store (dead); block-reduce per-graph
//     partial sums (<=2 graphs per 16-node block, batch sorted) + atomicAdd
//     into one of PSL pooled slots.
__global__ __launch_bounds__(256) void k_agg(
    const unsigned short* __restrict__ hWb,
    const int* __restrict__ offs, const int* __restrict__ esrc,
    const float* __restrict__ a_s, const float* __restrict__ a_d,
    const float* __restrict__ bias, unsigned short* __restrict__ hb,
    float* __restrict__ part, const float* __restrict__ gw,
    const float* __restrict__ gb, const float* __restrict__ gms,
    float* __restrict__ alpha, float* __restrict__ beta, float inv_n,
    int* __restrict__ ctr, const int* __restrict__ batch,
    float* __restrict__ pooled, int n) {
    __shared__ float ss[256][9];
    __shared__ float sq[256][9];
    __shared__ int lastFlag;
    const int tid = threadIdx.x;
    const int l16 = tid & 15;
    const int d = blockIdx.x * 16 + (tid >> 4);   // one node per 16-lane group
    const bool active = d < n;

    f32x2 acc0 = {0.f, 0.f}, acc1 = {0.f, 0.f}, acc2 = {0.f, 0.f}, acc3 = {0.f, 0.f};
    float ssum = 0.f;
    float h0 = 0.f, h1 = 0.f, h2 = 0.f, h3 = 0.f, h4 = 0.f, h5 = 0.f, h6 = 0.f, h7 = 0.f;

    if (active) {
        const int p0 = offs[d], p1 = offs[d + 1];
        const float ad = a_d[d];
        const uint4* hW8 = (const uint4*)hWb;

        // 1-deep software pipeline: row/score of edge p prefetched during edge p-1
        int s_cur = (p0 < p1) ? esrc[p0] : 0;
        uint4 raw = hW8[(size_t)s_cur * 16 + l16];
        float as_cur = a_s[s_cur];
        for (int p = p0; p < p1; ++p) {
            const uint4 r = raw;
            const float e = leaky(as_cur + ad, 0.2f);
            const int pn = (p + 1 < p1) ? p + 1 : p;
            const int s_nxt = esrc[pn];
            raw = hW8[(size_t)s_nxt * 16 + l16];
            as_cur = a_s[s_nxt];

            const float ex = __expf(e);
            ssum += ex;
            const f32x2 exv = {ex, ex};
            f32x2 v;
            v.x = f_of_bf16(r.x & 0xffff); v.y = f_of_bf16(r.x >> 16);
            acc0 = __builtin_elementwise_fma(exv, v, acc0);
            v.x = f_of_bf16(r.y & 0xffff); v.y = f_of_bf16(r.y >> 16);
            acc1 = __builtin_elementwise_fma(exv, v, acc1);
            v.x = f_of_bf16(r.z & 0xffff); v.y = f_of_bf16(r.z >> 16);
            acc2 = __builtin_elementwise_fma(exv, v, acc2);
            v.x = f_of_bf16(r.w & 0xffff); v.y = f_of_bf16(r.w >> 16);
            acc3 = __builtin_elementwise_fma(exv, v, acc3);
        }

        const float inv = 1.f / (ssum + 1e-16f);
        const float4* b4p = (const float4*)bias;
        const float4 bb0 = b4p[l16 * 2], bb1 = b4p[l16 * 2 + 1];
        h0 = fmaf(acc0.x, inv, bb0.x); h1 = fmaf(acc0.y, inv, bb0.y);
        h2 = fmaf(acc1.x, inv, bb0.z); h3 = fmaf(acc1.y, inv, bb0.w);
        h4 = fmaf(acc2.x, inv, bb1.x); h5 = fmaf(acc2.y, inv, bb1.y);
        h6 = fmaf(acc3.x, inv, bb1.z); h7 = fmaf(acc3.y, inv, bb1.w);
        if (part != nullptr) {   // layers 0,1 feed the next GEMM; layer 2's hb is dead
            uint4 o;
            o.x = (unsigned)bf16_of(h0) | ((unsigned)bf16_of(h1) << 16);
            o.y = (unsigned)bf16_of(h2) | ((unsigned)bf16_of(h3) << 16);
            o.z = (unsigned)bf16_of(h4) | ((unsigned)bf16_of(h5) << 16);
            o.w = (unsigned)bf16_of(h6) | ((unsigned)bf16_of(h7) << 16);
            ((uint4*)hb)[(size_t)d * 16 + l16] = o;
        }
    }

    if (part != nullptr) {
        // ---- GraphNorm stats tail (colstat layout: tid holds cols l16*8+k) ----
        ss[tid][0] = active ? h0 : 0.f; sq[tid][0] = active ? h0 * h0 : 0.f;
        ss[tid][1] = active ? h1 : 0.f; sq[tid][1] = active ? h1 * h1 : 0.f;
        ss[tid][2] = active ? h2 : 0.f; sq[tid][2] = active ? h2 * h2 : 0.f;
        ss[tid][3] = active ? h3 : 0.f; sq[tid][3] = active ? h3 * h3 : 0.f;
        ss[tid][4] = active ? h4 : 0.f; sq[tid][4] = active ? h4 * h4 : 0.f;
        ss[tid][5] = active ? h5 : 0.f; sq[tid][5] = active ? h5 * h5 : 0.f;
        ss[tid][6] = active ? h6 : 0.f; sq[tid][6] = active ? h6 * h6 : 0.f;
        ss[tid][7] = active ? h7 : 0.f; sq[tid][7] = active ? h7 * h7 : 0.f;
        __syncthreads();
        if (tid < 128) {
            int c = tid >> 3, k = tid & 7;     // col = c*8 + k = tid
            float S = 0.f, Q = 0.f;
#pragma unroll
            for (int g = 0; g < 16; ++g) {
                S += ss[g * 16 + c][k];
                Q += sq[g * 16 + c][k];
            }
            float* pslot = part + (size_t)(blockIdx.x & (CSB - 1)) * 256;
            atomicAdd(&pslot[tid], S);
            atomicAdd(&pslot[128 + tid], Q);
        }
        // ---- last-block-done: fold k_colfin in ----
        __syncthreads();          // drain this block's atomics (vmcnt(0) at barrier)
        __threadfence();
        if (tid == 0) lastFlag = (atomicAdd(ctr, 1) == (int)gridDim.x - 1) ? 1 : 0;
        __syncthreads();
        if (lastFlag) {
            __threadfence();      // invalidate L1; acquire other blocks' part adds
            float a0 = 0.f, a1 = 0.f, a2 = 0.f, a3 = 0.f;
            for (int b = 0; b < CSB; b += 4) {
                a0 += part[(b + 0) * 256 + tid];
                a1 += part[(b + 1) * 256 + tid];
                a2 += part[(b + 2) * 256 + tid];
                a3 += part[(b + 3) * 256 + tid];
            }
            ss[tid][0] = (a0 + a1) + (a2 + a3);
            __syncthreads();
            if (tid < 128) {
                float mean = ss[tid][0] * inv_n;
                float ex2 = ss[128 + tid][0] * inv_n;
                float m2 = mean * gms[tid];
                float var = ex2 - 2.f * m2 * mean + m2 * m2;
                float a = gw[tid] * rsqrtf(var + 1e-5f);
                alpha[tid] = a;
                beta[tid] = gb[tid] - m2 * a;
            }
        }
    } else if (pooled != nullptr) {
        // ---- global_add_pool tail: <=2 graphs per block (batch sorted) ----
        const int nb0 = blockIdx.x * 16;
        const int g0 = batch[nb0 < n ? nb0 : (n - 1)];
        const int g1 = batch[(nb0 + 15) < n ? (nb0 + 15) : (n - 1)];
        const bool isg0 = active && (batch[d] == g0);
        const bool isg1 = active && !isg0;
        ss[tid][0] = isg0 ? h0 : 0.f; sq[tid][0] = isg1 ? h0 : 0.f;
        ss[tid][1] = isg0 ? h1 : 0.f; sq[tid][1] = isg1 ? h1 : 0.f;
        ss[tid][2] = isg0 ? h2 : 0.f; sq[tid][2] = isg1 ? h2 : 0.f;
        ss[tid][3] = isg0 ? h3 : 0.f; sq[tid][3] = isg1 ? h3 : 0.f;
        ss[tid][4] = isg0 ? h4 : 0.f; sq[tid][4] = isg1 ? h4 : 0.f;
        ss[tid][5] = isg0 ? h5 : 0.f; sq[tid][5] = isg1 ? h5 : 0.f;
        ss[tid][6] = isg0 ? h6 : 0.f; sq[tid][6] = isg1 ? h6 : 0.f;
        ss[tid][7] = isg0 ? h7 : 0.f; sq[tid][7] = isg1 ? h7 : 0.f;
        __syncthreads();
        if (tid < 128) {
            int c = tid >> 3, k = tid & 7;     // col = tid
            float S = 0.f, Q = 0.f;
#pragma unroll
            for (int g = 0; g < 16; ++g) {
                S += ss[g * 16 + c][k];
                Q += sq[g * 16 + c][k];
            }
            float* slot = pooled + (size_t)(blockIdx.x & (PSL - 1)) * (GG * HD);
            atomicAdd(&slot[g0 * HD + tid], S);
            if (g1 != g0) atomicAdd(&slot[g1 * HD + tid], Q);
        }
    }
}

// ---------------- final MLP (sums the PSL pooled partial slots) ----------------
__global__ __launch_bounds__(128) void k_mlp(const float* __restrict__ pooled,
                                             const float* __restrict__ W1,
                                             const float* __restrict__ b1,
                                             const float* __restrict__ W2,
                                             const float* __restrict__ b2,
                                             float* __restrict__ out) {
    __shared__ float pr[HD];
    __shared__ float zs[HD];
    int g = blockIdx.x, t = threadIdx.x;
    float pv = 0.f;
#pragma unroll
    for (int k = 0; k < PSL; ++k) pv += pooled[(k * GG + g) * HD + t];
    pr[t] = pv;
    __syncthreads();
    float acc = b1[t];
#pragma unroll 8
    for (int k = 0; k < HD; ++k) acc = fmaf(pr[k], W1[k * HD + t], acc);
    zs[t] = leaky(acc, 0.01f);
    __syncthreads();
    if (t < 64) {
        float a2 = b2[t];
#pragma unroll 8
        for (int k = 0; k < HD; ++k) a2 = fmaf(zs[k], W2[k * 64 + t], a2);
        out[g * 64 + t] = a2;
    }
}

extern "C" void kernel_launch(void* const* d_in, const int* in_sizes, int n_in,
                              void* d_out, int out_size, void* d_ws, size_t ws_size,
                              hipStream_t stream) {
    const float* x        = (const float*)d_in[0];
    const int*   ei       = (const int*)d_in[1];
    const int*   batch    = (const int*)d_in[2];
    const float* Ws       = (const float*)d_in[3];
    const float* att_src  = (const float*)d_in[4];
    const float* att_dst  = (const float*)d_in[5];
    const float* conv_bias= (const float*)d_in[6];
    const float* gn_w     = (const float*)d_in[7];
    const float* gn_b     = (const float*)d_in[8];
    const float* gn_ms    = (const float*)d_in[9];
    const float* W1       = (const float*)d_in[10];
    const float* b1       = (const float*)d_in[11];
    const float* W2       = (const float*)d_in[12];
    const float* b2       = (const float*)d_in[13];
    float* out = (float*)d_out;

    const int n = in_sizes[2];       // 100000
    const int e = in_sizes[1] / 2;   // 600000
    const int* src = ei;
    const int* dst = ei + e;
    const int nbk = (n + 511) >> 9;  // 512-node buckets (n <= 262144 for ebuf packing)

    char* ws = (char*)d_ws;
    unsigned short* hWb = (unsigned short*)ws;                    // n*128 bf16
    unsigned short* hb  = hWb + (size_t)n * HD;                   // n*128 bf16
    float* a_s    = (float*)(hb + (size_t)n * HD);                // n
    float* a_d    = a_s + n;                                      // n
    float* alpha  = a_d + n;                                      // 128
    float* beta   = alpha + HD;                                   // 128
    float* pooled = beta + HD;                                    // PSL*GG*128
    float* part   = pooled + PSL * GG * HD;                       // 2*CSB*256
    unsigned short* Wt = (unsigned short*)(part + 2 * CSB * 256); // 3*128*128
    int* offs     = (int*)(Wt + 3 * 16384);                       // n+1
    int* esrc     = offs + n + 1;                                 // e
    int* ebuf     = esrc + e;                                     // e
    int* bcnt     = ebuf + e;                                     // 513
    int* bbase    = bcnt + 513;                                   // 514
    int* bcur     = bbase + 514;                                  // 513
    int* ctr      = bcur + 513;                                   // 2

    float* part0 = part;
    float* part1 = part + CSB * 256;

    // ---- init (weights->bf16 transposed + zero counters/partials) ----
    k_init<<<512, 256, 0, stream>>>(Ws, Wt, bcnt, part, pooled, ctr);
    // ---- bucketed CSR build ----
    k_bcount<<<256, 256, 0, stream>>>(dst, bcnt, e);
    k_bscan<<<1, 512, 0, stream>>>(bcnt, bbase, bcur, offs, nbk, n, e);
    k_part<<<256, 256, 0, stream>>>(src, dst, bcur, ebuf, e);
    k_bscatter<<<nbk, 256, 0, stream>>>(ebuf, bbase, offs, esrc, n);

    // ---- GAT layers ----
    for (int l = 0; l < 3; ++l) {
        if (l == 0) {
            k_gemm_a32<<<(n + 63) / 64, 256, 0, stream>>>(
                x, Wt, att_src, att_dst, hWb, a_s, a_d, n);
        } else {
            k_gemm_a16<<<(n + 63) / 64, 256, 0, stream>>>(
                hb, Wt + l * 16384, att_src + l * HD, att_dst + l * HD,
                alpha, beta, hWb, a_s, a_d, n);
        }
        if (l < 2) {
            float* lpart = (l == 0) ? part0 : part1;
            k_agg<<<(n + 15) / 16, 256, 0, stream>>>(
                hWb, offs, esrc, a_s, a_d, conv_bias + l * HD, hb,
                lpart, gn_w + l * HD, gn_b + l * HD, gn_ms + l * HD,
                alpha, beta, 1.0f / n, ctr + l, batch, nullptr, n);
        } else {
            k_agg<<<(n + 15) / 16, 256, 0, stream>>>(
                hWb, offs, esrc, a_s, a_d, conv_bias + l * HD, hb,
                nullptr, nullptr, nullptr, nullptr,
                nullptr, nullptr, 0.f, nullptr, batch, pooled, n);
        }
    }

    // ---- MLP (sums pooled partial slots) ----
    k_mlp<<<GG, HD, 0, stream>>>(pooled, W1, b1, W2, b2, out);
}

// Round 7
// 334.524 us; speedup vs baseline: 4.2727x; 4.2727x over previous
//
#include <hip/hip_runtime.h>
#include <math.h>

#define HD 128
#define GG 64
#define CSB 256   // colstat partial slots (per layer)
#define PSL 8     // pooled partial slots

typedef __attribute__((ext_vector_type(8))) short short8;
typedef __attribute__((ext_vector_type(4))) float f32x4;
typedef __attribute__((ext_vector_type(2))) float f32x2;

__device__ __forceinline__ float leaky(float x, float s) { return x > 0.f ? x : s * x; }

__device__ __forceinline__ unsigned short bf16_of(float f) {
    union { float f; unsigned u; } v; v.f = f;
    unsigned r = v.u + 0x7fffu + ((v.u >> 16) & 1u);
    return (unsigned short)(r >> 16);
}
__device__ __forceinline__ float f_of_bf16(unsigned short u) {
    union { unsigned u; float f; } v; v.u = ((unsigned)u) << 16;
    return v.f;
}

// XOR-swizzled LDS addressing for the 128x128 bf16 W tile (16B chunks).
__device__ __forceinline__ int sw(int row, int chunk) {
    return row * 128 + ((chunk ^ (row & 15)) << 3);
}

// -------- init: W->Wt bf16 transposed + zero bucket counters / part / pooled --------
__global__ void k_init(const float* __restrict__ Ws, unsigned short* __restrict__ Wt,
                       int* __restrict__ bcnt, float* __restrict__ part,
                       float* __restrict__ pooled) {
    int i = blockIdx.x * 256 + threadIdx.x;   // grid 768*256 = 196608
    if (i < 3 * 16384) {
        int l = i >> 14, rem = i & 16383;
        int nn = rem >> 7, k = rem & 127;
        Wt[i] = bf16_of(Ws[l * 16384 + k * 128 + nn]);
    }
    if (i < 513) bcnt[i] = 0;
    if (i < 2 * CSB * 256) part[i] = 0.f;     // 131072
    if (i < PSL * GG * HD) pooled[i] = 0.f;   // 65536
}

// ================= register-A + LDS-B MFMA GEMM, 64-row blocks =============
// (round-1 form: mfma(af, bfr); per-reg epilogue with 16-lane shuffle att dots)

// ---- variant A: fp32 input (layer 0, no norm) ----
__global__ __launch_bounds__(256) void k_gemm_a32(
    const float* __restrict__ A, const unsigned short* __restrict__ Wt,
    const float* __restrict__ att_s, const float* __restrict__ att_d,
    unsigned short* __restrict__ hWb, float* __restrict__ a_s, float* __restrict__ a_d,
    int n) {
    __shared__ unsigned short Bs[128 * 128];
    const int tid = threadIdx.x;
    const int base = blockIdx.x * 64;

    const uint4* Wt4 = (const uint4*)Wt;
    uint4* Bs4 = (uint4*)Bs;
#pragma unroll
    for (int j = 0; j < 8; ++j) {
        int flat = tid + j * 256;
        int col = flat >> 4, c8 = flat & 15;
        Bs4[(col << 4) + (c8 ^ (col & 15))] = Wt4[flat];
    }

    const int wave = tid >> 6, lane = tid & 63;
    const int m16 = lane & 15, quad = lane >> 4;

    short8 af[4];
    {
        int row = base + wave * 16 + m16;
        row = (row < n) ? row : (n - 1);
        const float4* ap = (const float4*)(A + (size_t)row * 128);
#pragma unroll
        for (int kk = 0; kk < 4; ++kk) {
            float4 v0 = ap[kk * 8 + quad * 2];
            float4 v1 = ap[kk * 8 + quad * 2 + 1];
            union { short8 s; unsigned u[4]; } P;
            P.u[0] = (unsigned)bf16_of(v0.x) | ((unsigned)bf16_of(v0.y) << 16);
            P.u[1] = (unsigned)bf16_of(v0.z) | ((unsigned)bf16_of(v0.w) << 16);
            P.u[2] = (unsigned)bf16_of(v1.x) | ((unsigned)bf16_of(v1.y) << 16);
            P.u[3] = (unsigned)bf16_of(v1.z) | ((unsigned)bf16_of(v1.w) << 16);
            af[kk] = P.s;
        }
    }
    __syncthreads();

    f32x4 acc[8];
#pragma unroll
    for (int ct = 0; ct < 8; ++ct) acc[ct] = (f32x4){0.f, 0.f, 0.f, 0.f};
#pragma unroll
    for (int kk = 0; kk < 4; ++kk) {
#pragma unroll
        for (int ct = 0; ct < 8; ++ct) {
            short8 bfr = *(const short8*)&Bs[sw(ct * 16 + m16, kk * 4 + quad)];
            acc[ct] = __builtin_amdgcn_mfma_f32_16x16x32_bf16(af[kk], bfr, acc[ct], 0, 0, 0);
        }
    }

#pragma unroll
    for (int reg = 0; reg < 4; ++reg) {
        int gr = base + wave * 16 + quad * 4 + reg;
        bool ok = gr < n;
        unsigned short* rowp = hWb + (size_t)gr * 128 + m16;
        float s = 0.f, dd = 0.f;
#pragma unroll
        for (int ct = 0; ct < 8; ++ct) {
            float v = acc[ct][reg];
            int col = ct * 16 + m16;
            if (ok) rowp[ct * 16] = bf16_of(v);
            s = fmaf(v, att_s[col], s);
            dd = fmaf(v, att_d[col], dd);
        }
#pragma unroll
        for (int off = 1; off < 16; off <<= 1) {
            s += __shfl_xor(s, off, 64);
            dd += __shfl_xor(dd, off, 64);
        }
        if (m16 == 0 && ok) { a_s[gr] = s; a_d[gr] = dd; }
    }
}

// ---- variant B: bf16 input + GraphNorm affine + leaky (layers 1,2) ----
__global__ __launch_bounds__(256) void k_gemm_a16(
    const unsigned short* __restrict__ Ab, const unsigned short* __restrict__ Wt,
    const float* __restrict__ att_s, const float* __restrict__ att_d,
    const float* __restrict__ alpha, const float* __restrict__ beta,
    unsigned short* __restrict__ hWb, float* __restrict__ a_s, float* __restrict__ a_d,
    int n) {
    __shared__ unsigned short Bs[128 * 128];
    const int tid = threadIdx.x;
    const int base = blockIdx.x * 64;

    const uint4* Wt4 = (const uint4*)Wt;
    uint4* Bs4 = (uint4*)Bs;
#pragma unroll
    for (int j = 0; j < 8; ++j) {
        int flat = tid + j * 256;
        int col = flat >> 4, c8 = flat & 15;
        Bs4[(col << 4) + (c8 ^ (col & 15))] = Wt4[flat];
    }

    const int wave = tid >> 6, lane = tid & 63;
    const int m16 = lane & 15, quad = lane >> 4;
    const float4* al4 = (const float4*)alpha;
    const float4* be4 = (const float4*)beta;

    short8 af[4];
    {
        int row = base + wave * 16 + m16;
        row = (row < n) ? row : (n - 1);
        const uint4* ap = (const uint4*)(Ab + (size_t)row * 128);
#pragma unroll
        for (int kk = 0; kk < 4; ++kk) {
            uint4 raw = ap[kk * 4 + quad];
            int c4 = kk * 8 + quad * 2;
            float4 a0 = al4[c4], a1 = al4[c4 + 1];
            float4 b0 = be4[c4], b1 = be4[c4 + 1];
            float f0 = leaky(fmaf(f_of_bf16(raw.x & 0xffff), a0.x, b0.x), 0.01f);
            float f1 = leaky(fmaf(f_of_bf16(raw.x >> 16),    a0.y, b0.y), 0.01f);
            float f2 = leaky(fmaf(f_of_bf16(raw.y & 0xffff), a0.z, b0.z), 0.01f);
            float f3 = leaky(fmaf(f_of_bf16(raw.y >> 16),    a0.w, b0.w), 0.01f);
            float f4 = leaky(fmaf(f_of_bf16(raw.z & 0xffff), a1.x, b1.x), 0.01f);
            float f5 = leaky(fmaf(f_of_bf16(raw.z >> 16),    a1.y, b1.y), 0.01f);
            float f6 = leaky(fmaf(f_of_bf16(raw.w & 0xffff), a1.z, b1.z), 0.01f);
            float f7 = leaky(fmaf(f_of_bf16(raw.w >> 16),    a1.w, b1.w), 0.01f);
            union { short8 s; unsigned u[4]; } P;
            P.u[0] = (unsigned)bf16_of(f0) | ((unsigned)bf16_of(f1) << 16);
            P.u[1] = (unsigned)bf16_of(f2) | ((unsigned)bf16_of(f3) << 16);
            P.u[2] = (unsigned)bf16_of(f4) | ((unsigned)bf16_of(f5) << 16);
            P.u[3] = (unsigned)bf16_of(f6) | ((unsigned)bf16_of(f7) << 16);
            af[kk] = P.s;
        }
    }
    __syncthreads();

    f32x4 acc[8];
#pragma unroll
    for (int ct = 0; ct < 8; ++ct) acc[ct] = (f32x4){0.f, 0.f, 0.f, 0.f};
#pragma unroll
    for (int kk = 0; kk < 4; ++kk) {
#pragma unroll
        for (int ct = 0; ct < 8; ++ct) {
            short8 bfr = *(const short8*)&Bs[sw(ct * 16 + m16, kk * 4 + quad)];
            acc[ct] = __builtin_amdgcn_mfma_f32_16x16x32_bf16(af[kk], bfr, acc[ct], 0, 0, 0);
        }
    }

#pragma unroll
    for (int reg = 0; reg < 4; ++reg) {
        int gr = base + wave * 16 + quad * 4 + reg;
        bool ok = gr < n;
        unsigned short* rowp = hWb + (size_t)gr * 128 + m16;
        float s = 0.f, dd = 0.f;
#pragma unroll
        for (int ct = 0; ct < 8; ++ct) {
            float v = acc[ct][reg];
            int col = ct * 16 + m16;
            if (ok) rowp[ct * 16] = bf16_of(v);
            s = fmaf(v, att_s[col], s);
            dd = fmaf(v, att_d[col], dd);
        }
#pragma unroll
        for (int off = 1; off < 16; off <<= 1) {
            s += __shfl_xor(s, off, 64);
            dd += __shfl_xor(dd, off, 64);
        }
        if (m16 == 0 && ok) { a_s[gr] = s; a_d[gr] = dd; }
    }
}

// ================= bucketed CSR build (LDS atomics, compact writes) =============
// Buckets of 512 nodes: bucket b = dst >> 9, local id = dst & 511.
// ebuf packs (local << 18) | src  (valid for n <= 262144).

__global__ __launch_bounds__(256) void k_bcount(const int* __restrict__ dst,
                                                int* __restrict__ bcnt, int e) {
    __shared__ int lh[512];
    const int tid = threadIdx.x;
    for (int t = tid; t < 512; t += 256) lh[t] = 0;
    __syncthreads();
    for (int i = blockIdx.x * 256 + tid; i < e; i += gridDim.x * 256)
        atomicAdd(&lh[dst[i] >> 9], 1);
    __syncthreads();
    for (int t = tid; t < 512; t += 256)
        if (lh[t]) atomicAdd(&bcnt[t], lh[t]);
}

__global__ void k_bscan(const int* __restrict__ bcnt, int* __restrict__ bbase,
                        int* __restrict__ bcur, int* __restrict__ offs,
                        int nbk, int n, int e) {
    __shared__ int s[512];
    int t = threadIdx.x;
    int v = (t < nbk) ? bcnt[t] : 0;
    s[t] = v;
    __syncthreads();
    for (int off = 1; off < 512; off <<= 1) {
        int u = (t >= off) ? s[t - off] : 0;
        __syncthreads();
        s[t] += u;
        __syncthreads();
    }
    if (t < nbk) { bbase[t] = s[t] - v; bcur[t] = s[t] - v; }
    if (t == 0) { bbase[nbk] = e; offs[n] = e; }
}

__global__ __launch_bounds__(256) void k_part(const int* __restrict__ src,
                                              const int* __restrict__ dst,
                                              int* __restrict__ bcur,
                                              int* __restrict__ ebuf, int e) {
    __shared__ int lh[512];
    __shared__ int lbase[512];
    const int tid = threadIdx.x;
    const int chunk = (e + gridDim.x - 1) / gridDim.x;
    const int i0 = blockIdx.x * chunk;
    const int i1 = min(e, i0 + chunk);
    for (int t = tid; t < 512; t += 256) lh[t] = 0;
    __syncthreads();
    for (int i = i0 + tid; i < i1; i += 256) atomicAdd(&lh[dst[i] >> 9], 1);
    __syncthreads();
    for (int t = tid; t < 512; t += 256) {
        int c = lh[t];
        lbase[t] = c ? atomicAdd(&bcur[t], c) : 0;
    }
    __syncthreads();
    for (int t = tid; t < 512; t += 256) lh[t] = 0;
    __syncthreads();
    for (int i = i0 + tid; i < i1; i += 256) {
        int d = dst[i];
        int b = d >> 9;
        int p = lbase[b] + atomicAdd(&lh[b], 1);
        ebuf[p] = ((d & 511) << 18) | src[i];
    }
}

__global__ __launch_bounds__(256) void k_bscatter(const int* __restrict__ ebuf,
                                                  const int* __restrict__ bbase,
                                                  int* __restrict__ offs,
                                                  int* __restrict__ esrc, int n) {
    const int b = blockIdx.x;
    const int tid = threadIdx.x;
    const int nb0 = b << 9;
    const int e0 = bbase[b], e1 = bbase[b + 1];
    __shared__ int cnt[512];
    __shared__ int sc[512];
    __shared__ int pos[512];
    for (int t = tid; t < 512; t += 256) cnt[t] = 0;
    __syncthreads();
    for (int i = e0 + tid; i < e1; i += 256) atomicAdd(&cnt[ebuf[i] >> 18], 1);
    __syncthreads();
    for (int t = tid; t < 512; t += 256) sc[t] = cnt[t];
    __syncthreads();
    for (int off = 1; off < 512; off <<= 1) {
        int t0 = tid, t1 = tid + 256;
        int v0 = (t0 >= off) ? sc[t0 - off] : 0;
        int v1 = sc[t1 - off];
        __syncthreads();
        sc[t0] += v0;
        sc[t1] += v1;
        __syncthreads();
    }
    for (int t = tid; t < 512; t += 256) pos[t] = e0 + sc[t] - cnt[t];
    __syncthreads();
    for (int t = tid; t < 512; t += 256) {
        int node = nb0 + t;
        if (node < n) offs[node] = pos[t];
    }
    __syncthreads();
    for (int i = e0 + tid; i < e1; i += 256) {
        int v = ebuf[i];
        int l = v >> 18;
        int p = atomicAdd(&pos[l], 1);
        esrc[p] = v & 0x3FFFF;
    }
}

// ---------------- fused attention softmax + aggregation -------------------
// One 16-lane group per destination node. Tails (NO fences, NO device counters):
//   part != nullptr (layers 0,1): write bf16 h + GraphNorm stats block-reduce +
//     atomicAdd into part slot. alpha/beta computed by separate k_colfin launch.
//   pooled != nullptr (layer 2): NO h store (dead); block-reduce per-graph
//     partial sums (<=2 graphs per 16-node block, batch sorted) + atomicAdd
//     into one of PSL pooled slots.
__global__ __launch_bounds__(256) void k_agg(
    const unsigned short* __restrict__ hWb,
    const int* __restrict__ offs, const int* __restrict__ esrc,
    const float* __restrict__ a_s, const float* __restrict__ a_d,
    const float* __restrict__ bias, unsigned short* __restrict__ hb,
    float* __restrict__ part, const int* __restrict__ batch,
    float* __restrict__ pooled, int n) {
    __shared__ float ss[256][9];
    __shared__ float sq[256][9];
    const int tid = threadIdx.x;
    const int l16 = tid & 15;
    const int d = blockIdx.x * 16 + (tid >> 4);   // one node per 16-lane group
    const bool active = d < n;

    f32x2 acc0 = {0.f, 0.f}, acc1 = {0.f, 0.f}, acc2 = {0.f, 0.f}, acc3 = {0.f, 0.f};
    float ssum = 0.f;
    float h0 = 0.f, h1 = 0.f, h2 = 0.f, h3 = 0.f, h4 = 0.f, h5 = 0.f, h6 = 0.f, h7 = 0.f;

    if (active) {
        const int p0 = offs[d], p1 = offs[d + 1];
        const float ad = a_d[d];
        const uint4* hW8 = (const uint4*)hWb;

        // 1-deep software pipeline: row/score of edge p prefetched during edge p-1
        int s_cur = (p0 < p1) ? esrc[p0] : 0;
        uint4 raw = hW8[(size_t)s_cur * 16 + l16];
        float as_cur = a_s[s_cur];
        for (int p = p0; p < p1; ++p) {
            const uint4 r = raw;
            const float e = leaky(as_cur + ad, 0.2f);
            const int pn = (p + 1 < p1) ? p + 1 : p;
            const int s_nxt = esrc[pn];
            raw = hW8[(size_t)s_nxt * 16 + l16];
            as_cur = a_s[s_nxt];

            const float ex = __expf(e);
            ssum += ex;
            const f32x2 exv = {ex, ex};
            f32x2 v;
            v.x = f_of_bf16(r.x & 0xffff); v.y = f_of_bf16(r.x >> 16);
            acc0 = __builtin_elementwise_fma(exv, v, acc0);
            v.x = f_of_bf16(r.y & 0xffff); v.y = f_of_bf16(r.y >> 16);
            acc1 = __builtin_elementwise_fma(exv, v, acc1);
            v.x = f_of_bf16(r.z & 0xffff); v.y = f_of_bf16(r.z >> 16);
            acc2 = __builtin_elementwise_fma(exv, v, acc2);
            v.x = f_of_bf16(r.w & 0xffff); v.y = f_of_bf16(r.w >> 16);
            acc3 = __builtin_elementwise_fma(exv, v, acc3);
        }

        const float inv = 1.f / (ssum + 1e-16f);
        const float4* b4p = (const float4*)bias;
        const float4 bb0 = b4p[l16 * 2], bb1 = b4p[l16 * 2 + 1];
        h0 = fmaf(acc0.x, inv, bb0.x); h1 = fmaf(acc0.y, inv, bb0.y);
        h2 = fmaf(acc1.x, inv, bb0.z); h3 = fmaf(acc1.y, inv, bb0.w);
        h4 = fmaf(acc2.x, inv, bb1.x); h5 = fmaf(acc2.y, inv, bb1.y);
        h6 = fmaf(acc3.x, inv, bb1.z); h7 = fmaf(acc3.y, inv, bb1.w);
        if (part != nullptr) {   // layers 0,1 feed the next GEMM; layer 2's hb is dead
            uint4 o;
            o.x = (unsigned)bf16_of(h0) | ((unsigned)bf16_of(h1) << 16);
            o.y = (unsigned)bf16_of(h2) | ((unsigned)bf16_of(h3) << 16);
            o.z = (unsigned)bf16_of(h4) | ((unsigned)bf16_of(h5) << 16);
            o.w = (unsigned)bf16_of(h6) | ((unsigned)bf16_of(h7) << 16);
            ((uint4*)hb)[(size_t)d * 16 + l16] = o;
        }
    }

    if (part != nullptr) {
        // ---- GraphNorm stats tail (colstat layout: tid holds cols l16*8+k) ----
        ss[tid][0] = active ? h0 : 0.f; sq[tid][0] = active ? h0 * h0 : 0.f;
        ss[tid][1] = active ? h1 : 0.f; sq[tid][1] = active ? h1 * h1 : 0.f;
        ss[tid][2] = active ? h2 : 0.f; sq[tid][2] = active ? h2 * h2 : 0.f;
        ss[tid][3] = active ? h3 : 0.f; sq[tid][3] = active ? h3 * h3 : 0.f;
        ss[tid][4] = active ? h4 : 0.f; sq[tid][4] = active ? h4 * h4 : 0.f;
        ss[tid][5] = active ? h5 : 0.f; sq[tid][5] = active ? h5 * h5 : 0.f;
        ss[tid][6] = active ? h6 : 0.f; sq[tid][6] = active ? h6 * h6 : 0.f;
        ss[tid][7] = active ? h7 : 0.f; sq[tid][7] = active ? h7 * h7 : 0.f;
        __syncthreads();
        if (tid < 128) {
            int c = tid >> 3, k = tid & 7;     // col = c*8 + k = tid
            float S = 0.f, Q = 0.f;
#pragma unroll
            for (int g = 0; g < 16; ++g) {
                S += ss[g * 16 + c][k];
                Q += sq[g * 16 + c][k];
            }
            float* pslot = part + (size_t)(blockIdx.x & (CSB - 1)) * 256;
            atomicAdd(&pslot[tid], S);
            atomicAdd(&pslot[128 + tid], Q);
        }
    } else if (pooled != nullptr) {
        // ---- global_add_pool tail: <=2 graphs per block (batch sorted) ----
        const int nb0 = blockIdx.x * 16;
        const int g0 = batch[nb0 < n ? nb0 : (n - 1)];
        const int g1 = batch[(nb0 + 15) < n ? (nb0 + 15) : (n - 1)];
        const bool isg0 = active && (batch[d] == g0);
        const bool isg1 = active && !isg0;
        ss[tid][0] = isg0 ? h0 : 0.f; sq[tid][0] = isg1 ? h0 : 0.f;
        ss[tid][1] = isg0 ? h1 : 0.f; sq[tid][1] = isg1 ? h1 : 0.f;
        ss[tid][2] = isg0 ? h2 : 0.f; sq[tid][2] = isg1 ? h2 : 0.f;
        ss[tid][3] = isg0 ? h3 : 0.f; sq[tid][3] = isg1 ? h3 : 0.f;
        ss[tid][4] = isg0 ? h4 : 0.f; sq[tid][4] = isg1 ? h4 : 0.f;
        ss[tid][5] = isg0 ? h5 : 0.f; sq[tid][5] = isg1 ? h5 : 0.f;
        ss[tid][6] = isg0 ? h6 : 0.f; sq[tid][6] = isg1 ? h6 : 0.f;
        ss[tid][7] = isg0 ? h7 : 0.f; sq[tid][7] = isg1 ? h7 : 0.f;
        __syncthreads();
        if (tid < 128) {
            int c = tid >> 3, k = tid & 7;     // col = tid
            float S = 0.f, Q = 0.f;
#pragma unroll
            for (int g = 0; g < 16; ++g) {
                S += ss[g * 16 + c][k];
                Q += sq[g * 16 + c][k];
            }
            float* slot = pooled + (size_t)(blockIdx.x & (PSL - 1)) * (GG * HD);
            atomicAdd(&slot[g0 * HD + tid], S);
            if (g1 != g0) atomicAdd(&slot[g1 * HD + tid], Q);
        }
    }
}

// ---------------- reduce partials + alpha/beta (separate launch = free visibility) --
__global__ __launch_bounds__(256) void k_colfin(const float* __restrict__ part,
                                                const float* __restrict__ w,
                                                const float* __restrict__ bb,
                                                const float* __restrict__ ms,
                                                float* __restrict__ alpha,
                                                float* __restrict__ beta, float inv_n) {
    int tid = threadIdx.x;
    float a0 = 0.f, a1 = 0.f, a2 = 0.f, a3 = 0.f;
    for (int b = 0; b < CSB; b += 4) {
        a0 += part[(b + 0) * 256 + tid];
        a1 += part[(b + 1) * 256 + tid];
        a2 += part[(b + 2) * 256 + tid];
        a3 += part[(b + 3) * 256 + tid];
    }
    __shared__ float fin[256];
    fin[tid] = (a0 + a1) + (a2 + a3);
    __syncthreads();
    if (tid < 128) {
        float mean = fin[tid] * inv_n;
        float ex2 = fin[128 + tid] * inv_n;
        float m2 = mean * ms[tid];
        float var = ex2 - 2.f * m2 * mean + m2 * m2;
        float a = w[tid] * rsqrtf(var + 1e-5f);
        alpha[tid] = a;
        beta[tid] = bb[tid] - m2 * a;
    }
}

// ---------------- final MLP (sums the PSL pooled partial slots) ----------------
__global__ __launch_bounds__(128) void k_mlp(const float* __restrict__ pooled,
                                             const float* __restrict__ W1,
                                             const float* __restrict__ b1,
                                             const float* __restrict__ W2,
                                             const float* __restrict__ b2,
                                             float* __restrict__ out) {
    __shared__ float pr[HD];
    __shared__ float zs[HD];
    int g = blockIdx.x, t = threadIdx.x;
    float pv = 0.f;
#pragma unroll
    for (int k = 0; k < PSL; ++k) pv += pooled[(k * GG + g) * HD + t];
    pr[t] = pv;
    __syncthreads();
    float acc = b1[t];
#pragma unroll 8
    for (int k = 0; k < HD; ++k) acc = fmaf(pr[k], W1[k * HD + t], acc);
    zs[t] = leaky(acc, 0.01f);
    __syncthreads();
    if (t < 64) {
        float a2 = b2[t];
#pragma unroll 8
        for (int k = 0; k < HD; ++k) a2 = fmaf(zs[k], W2[k * 64 + t], a2);
        out[g * 64 + t] = a2;
    }
}

extern "C" void kernel_launch(void* const* d_in, const int* in_sizes, int n_in,
                              void* d_out, int out_size, void* d_ws, size_t ws_size,
                              hipStream_t stream) {
    const float* x        = (const float*)d_in[0];
    const int*   ei       = (const int*)d_in[1];
    const int*   batch    = (const int*)d_in[2];
    const float* Ws       = (const float*)d_in[3];
    const float* att_src  = (const float*)d_in[4];
    const float* att_dst  = (const float*)d_in[5];
    const float* conv_bias= (const float*)d_in[6];
    const float* gn_w     = (const float*)d_in[7];
    const float* gn_b     = (const float*)d_in[8];
    const float* gn_ms    = (const float*)d_in[9];
    const float* W1       = (const float*)d_in[10];
    const float* b1       = (const float*)d_in[11];
    const float* W2       = (const float*)d_in[12];
    const float* b2       = (const float*)d_in[13];
    float* out = (float*)d_out;

    const int n = in_sizes[2];       // 100000
    const int e = in_sizes[1] / 2;   // 600000
    const int* src = ei;
    const int* dst = ei + e;
    const int nbk = (n + 511) >> 9;  // 512-node buckets (n <= 262144 for ebuf packing)

    char* ws = (char*)d_ws;
    unsigned short* hWb = (unsigned short*)ws;                    // n*128 bf16
    unsigned short* hb  = hWb + (size_t)n * HD;                   // n*128 bf16
    float* a_s    = (float*)(hb + (size_t)n * HD);                // n
    float* a_d    = a_s + n;                                      // n
    float* alpha  = a_d + n;                                      // 128
    float* beta   = alpha + HD;                                   // 128
    float* pooled = beta + HD;                                    // PSL*GG*128
    float* part   = pooled + PSL * GG * HD;                       // 2*CSB*256
    unsigned short* Wt = (unsigned short*)(part + 2 * CSB * 256); // 3*128*128
    int* offs     = (int*)(Wt + 3 * 16384);                       // n+1
    int* esrc     = offs + n + 1;                                 // e
    int* ebuf     = esrc + e;                                     // e
    int* bcnt     = ebuf + e;                                     // 513
    int* bbase    = bcnt + 513;                                   // 514
    int* bcur     = bbase + 514;                                  // 513

    float* part0 = part;
    float* part1 = part + CSB * 256;

    // ---- init (weights->bf16 transposed + zero counters/partials) ----
    k_init<<<768, 256, 0, stream>>>(Ws, Wt, bcnt, part, pooled);
    // ---- bucketed CSR build ----
    k_bcount<<<256, 256, 0, stream>>>(dst, bcnt, e);
    k_bscan<<<1, 512, 0, stream>>>(bcnt, bbase, bcur, offs, nbk, n, e);
    k_part<<<256, 256, 0, stream>>>(src, dst, bcur, ebuf, e);
    k_bscatter<<<nbk, 256, 0, stream>>>(ebuf, bbase, offs, esrc, n);

    // ---- GAT layers ----
    for (int l = 0; l < 3; ++l) {
        if (l == 0) {
            k_gemm_a32<<<(n + 63) / 64, 256, 0, stream>>>(
                x, Wt, att_src, att_dst, hWb, a_s, a_d, n);
        } else {
            k_gemm_a16<<<(n + 63) / 64, 256, 0, stream>>>(
                hb, Wt + l * 16384, att_src + l * HD, att_dst + l * HD,
                alpha, beta, hWb, a_s, a_d, n);
        }
        if (l < 2) {
            float* lpart = (l == 0) ? part0 : part1;
            k_agg<<<(n + 15) / 16, 256, 0, stream>>>(
                hWb, offs, esrc, a_s, a_d, conv_bias + l * HD, hb,
                lpart, batch, nullptr, n);
            k_colfin<<<1, 256, 0, stream>>>(lpart, gn_w + l * HD, gn_b + l * HD,
                                            gn_ms + l * HD, alpha, beta, 1.0f / n);
        } else {
            k_agg<<<(n + 15) / 16, 256, 0, stream>>>(
                hWb, offs, esrc, a_s, a_d, conv_bias + l * HD, hb,
                nullptr, batch, pooled, n);
        }
    }

    // ---- MLP (sums pooled partial slots) ----
    k_mlp<<<GG, HD, 0, stream>>>(pooled, W1, b1, W2, b2, out);
}

// Round 8
// 318.460 us; speedup vs baseline: 4.4882x; 1.0504x over previous
//
#include <hip/hip_runtime.h>
#include <math.h>

#define HD 128
#define GG 64
#define CSB 256   // colstat partial slots (per layer)
#define PSL 8     // pooled partial slots

typedef __attribute__((ext_vector_type(8))) short short8;
typedef __attribute__((ext_vector_type(4))) float f32x4;
typedef __attribute__((ext_vector_type(2))) float f32x2;

__device__ __forceinline__ float leaky(float x, float s) { return x > 0.f ? x : s * x; }

__device__ __forceinline__ unsigned short bf16_of(float f) {
    union { float f; unsigned u; } v; v.f = f;
    unsigned r = v.u + 0x7fffu + ((v.u >> 16) & 1u);
    return (unsigned short)(r >> 16);
}
__device__ __forceinline__ float f_of_bf16(unsigned short u) {
    union { unsigned u; float f; } v; v.u = ((unsigned)u) << 16;
    return v.f;
}

// XOR-swizzled LDS addressing for the 128x128 bf16 W tile (16B chunks).
__device__ __forceinline__ int sw(int row, int chunk) {
    return row * 128 + ((chunk ^ (row & 15)) << 3);
}

// -------- init (blocks 0..511): W->Wt bf16 transposed + zero part/pooled
// -------- bcount (blocks 512..767): race-free per-block dst histograms -> bhist
__global__ __launch_bounds__(256) void k_initb(const float* __restrict__ Ws,
                                               unsigned short* __restrict__ Wt,
                                               float* __restrict__ part,
                                               float* __restrict__ pooled,
                                               const int* __restrict__ dst,
                                               int* __restrict__ bhist, int e) {
    const int tid = threadIdx.x;
    if (blockIdx.x >= 512) {
        __shared__ int lh[512];
        const int bi = blockIdx.x - 512;           // 0..255
        for (int t = tid; t < 512; t += 256) lh[t] = 0;
        __syncthreads();
        const int chunk = (e + 255) / 256;
        const int i0 = bi * chunk;
        const int i1 = min(e, i0 + chunk);
        for (int i = i0 + tid; i < i1; i += 256) atomicAdd(&lh[dst[i] >> 9], 1);
        __syncthreads();
        for (int t = tid; t < 512; t += 256) bhist[bi * 512 + t] = lh[t];
        return;
    }
    int i = blockIdx.x * 256 + tid;               // 0..131071
    if (i < 3 * 16384) {
        int l = i >> 14, rem = i & 16383;
        int nn = rem >> 7, k = rem & 127;
        Wt[i] = bf16_of(Ws[l * 16384 + k * 128 + nn]);
    }
    if (i < 2 * CSB * 256) part[i] = 0.f;         // 131072
    if (i < PSL * GG * HD) pooled[i] = 0.f;       // 65536
}

// ================= bucketed CSR build =============
// Buckets of 512 nodes: bucket b = dst >> 9, local id = dst & 511.
// ebuf packs (local << 18) | src  (valid for n <= 262144).

__global__ void k_bscan(const int* __restrict__ bhist, int* __restrict__ bbase,
                        int* __restrict__ bcur, int* __restrict__ offs,
                        int nbk, int n, int e) {
    __shared__ int s[512];
    int t = threadIdx.x;
    int v = 0;
    if (t < nbk) {
        for (int b = 0; b < 256; ++b) v += bhist[b * 512 + t];
    }
    s[t] = v;
    __syncthreads();
    for (int off = 1; off < 512; off <<= 1) {
        int u = (t >= off) ? s[t - off] : 0;
        __syncthreads();
        s[t] += u;
        __syncthreads();
    }
    if (t < nbk) { bbase[t] = s[t] - v; bcur[t] = s[t] - v; }
    if (t == 0) { bbase[nbk] = e; offs[n] = e; }
}

__global__ __launch_bounds__(256) void k_part(const int* __restrict__ src,
                                              const int* __restrict__ dst,
                                              int* __restrict__ bcur,
                                              int* __restrict__ ebuf, int e) {
    __shared__ int lh[512];
    __shared__ int lbase[512];
    const int tid = threadIdx.x;
    const int chunk = (e + gridDim.x - 1) / gridDim.x;
    const int i0 = blockIdx.x * chunk;
    const int i1 = min(e, i0 + chunk);
    for (int t = tid; t < 512; t += 256) lh[t] = 0;
    __syncthreads();
    for (int i = i0 + tid; i < i1; i += 256) atomicAdd(&lh[dst[i] >> 9], 1);
    __syncthreads();
    for (int t = tid; t < 512; t += 256) {
        int c = lh[t];
        lbase[t] = c ? atomicAdd(&bcur[t], c) : 0;
    }
    __syncthreads();
    for (int t = tid; t < 512; t += 256) lh[t] = 0;
    __syncthreads();
    for (int i = i0 + tid; i < i1; i += 256) {
        int d = dst[i];
        int b = d >> 9;
        int p = lbase[b] + atomicAdd(&lh[b], 1);
        ebuf[p] = ((d & 511) << 18) | src[i];
    }
}

// ================= fused: bscatter (blocks 0..nbk-1) + GEMM layer0 (rest) =========
// bscatter LDS (6KB) aliased onto the 32KB Bs tile -> GEMM occupancy unchanged.
__global__ __launch_bounds__(256) void k_gemm_a32_bsc(
    const float* __restrict__ A, const unsigned short* __restrict__ Wt,
    const float* __restrict__ att_s, const float* __restrict__ att_d,
    unsigned short* __restrict__ hWb, float* __restrict__ a_s, float* __restrict__ a_d,
    const int* __restrict__ ebuf, const int* __restrict__ bbase,
    int* __restrict__ offs, int* __restrict__ esrc, int nbk, int n) {
    __shared__ unsigned short Bs[128 * 128];
    const int tid = threadIdx.x;

    if (blockIdx.x < nbk) {
        // ---------------- bscatter role ----------------
        int* cnt = (int*)Bs;        // 512 ints
        int* sc  = cnt + 512;       // 512 ints
        int* pos = sc + 512;        // 512 ints (6KB total, < 32KB)
        const int b = blockIdx.x;
        const int nb0 = b << 9;
        const int e0 = bbase[b], e1 = bbase[b + 1];
        for (int t = tid; t < 512; t += 256) cnt[t] = 0;
        __syncthreads();
        for (int i = e0 + tid; i < e1; i += 256) atomicAdd(&cnt[ebuf[i] >> 18], 1);
        __syncthreads();
        for (int t = tid; t < 512; t += 256) sc[t] = cnt[t];
        __syncthreads();
        for (int off = 1; off < 512; off <<= 1) {
            int t0 = tid, t1 = tid + 256;
            int v0 = (t0 >= off) ? sc[t0 - off] : 0;
            int v1 = sc[t1 - off];
            __syncthreads();
            sc[t0] += v0;
            sc[t1] += v1;
            __syncthreads();
        }
        for (int t = tid; t < 512; t += 256) pos[t] = e0 + sc[t] - cnt[t];
        __syncthreads();
        for (int t = tid; t < 512; t += 256) {
            int node = nb0 + t;
            if (node < n) offs[node] = pos[t];
        }
        __syncthreads();
        for (int i = e0 + tid; i < e1; i += 256) {
            int v = ebuf[i];
            int l = v >> 18;
            int p = atomicAdd(&pos[l], 1);
            esrc[p] = v & 0x3FFFF;
        }
        return;
    }

    // ---------------- GEMM role (round-1 form) ----------------
    const int base = (blockIdx.x - nbk) * 64;

    const uint4* Wt4 = (const uint4*)Wt;
    uint4* Bs4 = (uint4*)Bs;
#pragma unroll
    for (int j = 0; j < 8; ++j) {
        int flat = tid + j * 256;
        int col = flat >> 4, c8 = flat & 15;
        Bs4[(col << 4) + (c8 ^ (col & 15))] = Wt4[flat];
    }

    const int wave = tid >> 6, lane = tid & 63;
    const int m16 = lane & 15, quad = lane >> 4;

    short8 af[4];
    {
        int row = base + wave * 16 + m16;
        row = (row < n) ? row : (n - 1);
        const float4* ap = (const float4*)(A + (size_t)row * 128);
#pragma unroll
        for (int kk = 0; kk < 4; ++kk) {
            float4 v0 = ap[kk * 8 + quad * 2];
            float4 v1 = ap[kk * 8 + quad * 2 + 1];
            union { short8 s; unsigned u[4]; } P;
            P.u[0] = (unsigned)bf16_of(v0.x) | ((unsigned)bf16_of(v0.y) << 16);
            P.u[1] = (unsigned)bf16_of(v0.z) | ((unsigned)bf16_of(v0.w) << 16);
            P.u[2] = (unsigned)bf16_of(v1.x) | ((unsigned)bf16_of(v1.y) << 16);
            P.u[3] = (unsigned)bf16_of(v1.z) | ((unsigned)bf16_of(v1.w) << 16);
            af[kk] = P.s;
        }
    }
    __syncthreads();

    f32x4 acc[8];
#pragma unroll
    for (int ct = 0; ct < 8; ++ct) acc[ct] = (f32x4){0.f, 0.f, 0.f, 0.f};
#pragma unroll
    for (int kk = 0; kk < 4; ++kk) {
#pragma unroll
        for (int ct = 0; ct < 8; ++ct) {
            short8 bfr = *(const short8*)&Bs[sw(ct * 16 + m16, kk * 4 + quad)];
            acc[ct] = __builtin_amdgcn_mfma_f32_16x16x32_bf16(af[kk], bfr, acc[ct], 0, 0, 0);
        }
    }

#pragma unroll
    for (int reg = 0; reg < 4; ++reg) {
        int gr = base + wave * 16 + quad * 4 + reg;
        bool ok = gr < n;
        unsigned short* rowp = hWb + (size_t)gr * 128 + m16;
        float s = 0.f, dd = 0.f;
#pragma unroll
        for (int ct = 0; ct < 8; ++ct) {
            float v = acc[ct][reg];
            int col = ct * 16 + m16;
            if (ok) rowp[ct * 16] = bf16_of(v);
            s = fmaf(v, att_s[col], s);
            dd = fmaf(v, att_d[col], dd);
        }
#pragma unroll
        for (int off = 1; off < 16; off <<= 1) {
            s += __shfl_xor(s, off, 64);
            dd += __shfl_xor(dd, off, 64);
        }
        if (m16 == 0 && ok) { a_s[gr] = s; a_d[gr] = dd; }
    }
}

// ---- GEMM variant B: bf16 input + GraphNorm affine + leaky (layers 1,2) ----
__global__ __launch_bounds__(256) void k_gemm_a16(
    const unsigned short* __restrict__ Ab, const unsigned short* __restrict__ Wt,
    const float* __restrict__ att_s, const float* __restrict__ att_d,
    const float* __restrict__ alpha, const float* __restrict__ beta,
    unsigned short* __restrict__ hWb, float* __restrict__ a_s, float* __restrict__ a_d,
    int n) {
    __shared__ unsigned short Bs[128 * 128];
    const int tid = threadIdx.x;
    const int base = blockIdx.x * 64;

    const uint4* Wt4 = (const uint4*)Wt;
    uint4* Bs4 = (uint4*)Bs;
#pragma unroll
    for (int j = 0; j < 8; ++j) {
        int flat = tid + j * 256;
        int col = flat >> 4, c8 = flat & 15;
        Bs4[(col << 4) + (c8 ^ (col & 15))] = Wt4[flat];
    }

    const int wave = tid >> 6, lane = tid & 63;
    const int m16 = lane & 15, quad = lane >> 4;
    const float4* al4 = (const float4*)alpha;
    const float4* be4 = (const float4*)beta;

    short8 af[4];
    {
        int row = base + wave * 16 + m16;
        row = (row < n) ? row : (n - 1);
        const uint4* ap = (const uint4*)(Ab + (size_t)row * 128);
#pragma unroll
        for (int kk = 0; kk < 4; ++kk) {
            uint4 raw = ap[kk * 4 + quad];
            int c4 = kk * 8 + quad * 2;
            float4 a0 = al4[c4], a1 = al4[c4 + 1];
            float4 b0 = be4[c4], b1 = be4[c4 + 1];
            float f0 = leaky(fmaf(f_of_bf16(raw.x & 0xffff), a0.x, b0.x), 0.01f);
            float f1 = leaky(fmaf(f_of_bf16(raw.x >> 16),    a0.y, b0.y), 0.01f);
            float f2 = leaky(fmaf(f_of_bf16(raw.y & 0xffff), a0.z, b0.z), 0.01f);
            float f3 = leaky(fmaf(f_of_bf16(raw.y >> 16),    a0.w, b0.w), 0.01f);
            float f4 = leaky(fmaf(f_of_bf16(raw.z & 0xffff), a1.x, b1.x), 0.01f);
            float f5 = leaky(fmaf(f_of_bf16(raw.z >> 16),    a1.y, b1.y), 0.01f);
            float f6 = leaky(fmaf(f_of_bf16(raw.w & 0xffff), a1.z, b1.z), 0.01f);
            float f7 = leaky(fmaf(f_of_bf16(raw.w >> 16),    a1.w, b1.w), 0.01f);
            union { short8 s; unsigned u[4]; } P;
            P.u[0] = (unsigned)bf16_of(f0) | ((unsigned)bf16_of(f1) << 16);
            P.u[1] = (unsigned)bf16_of(f2) | ((unsigned)bf16_of(f3) << 16);
            P.u[2] = (unsigned)bf16_of(f4) | ((unsigned)bf16_of(f5) << 16);
            P.u[3] = (unsigned)bf16_of(f6) | ((unsigned)bf16_of(f7) << 16);
            af[kk] = P.s;
        }
    }
    __syncthreads();

    f32x4 acc[8];
#pragma unroll
    for (int ct = 0; ct < 8; ++ct) acc[ct] = (f32x4){0.f, 0.f, 0.f, 0.f};
#pragma unroll
    for (int kk = 0; kk < 4; ++kk) {
#pragma unroll
        for (int ct = 0; ct < 8; ++ct) {
            short8 bfr = *(const short8*)&Bs[sw(ct * 16 + m16, kk * 4 + quad)];
            acc[ct] = __builtin_amdgcn_mfma_f32_16x16x32_bf16(af[kk], bfr, acc[ct], 0, 0, 0);
        }
    }

#pragma unroll
    for (int reg = 0; reg < 4; ++reg) {
        int gr = base + wave * 16 + quad * 4 + reg;
        bool ok = gr < n;
        unsigned short* rowp = hWb + (size_t)gr * 128 + m16;
        float s = 0.f, dd = 0.f;
#pragma unroll
        for (int ct = 0; ct < 8; ++ct) {
            float v = acc[ct][reg];
            int col = ct * 16 + m16;
            if (ok) rowp[ct * 16] = bf16_of(v);
            s = fmaf(v, att_s[col], s);
            dd = fmaf(v, att_d[col], dd);
        }
#pragma unroll
        for (int off = 1; off < 16; off <<= 1) {
            s += __shfl_xor(s, off, 64);
            dd += __shfl_xor(dd, off, 64);
        }
        if (m16 == 0 && ok) { a_s[gr] = s; a_d[gr] = dd; }
    }
}

// ---------------- fused attention softmax + aggregation -------------------
// One 16-lane group per destination node. Tails (NO fences, NO device counters):
//   part != nullptr (layers 0,1): write bf16 h + GraphNorm stats block-reduce +
//     atomicAdd into part slot. alpha/beta computed by separate k_colfin launch.
//   pooled != nullptr (layer 2): NO h store (dead); block-reduce per-graph
//     partial sums (<=2 graphs per 16-node block, batch sorted) + atomicAdd
//     into one of PSL pooled slots.
__global__ __launch_bounds__(256) void k_agg(
    const unsigned short* __restrict__ hWb,
    const int* __restrict__ offs, const int* __restrict__ esrc,
    const float* __restrict__ a_s, const float* __restrict__ a_d,
    const float* __restrict__ bias, unsigned short* __restrict__ hb,
    float* __restrict__ part, const int* __restrict__ batch,
    float* __restrict__ pooled, int n) {
    __shared__ float ss[256][9];
    __shared__ float sq[256][9];
    const int tid = threadIdx.x;
    const int l16 = tid & 15;
    const int d = blockIdx.x * 16 + (tid >> 4);   // one node per 16-lane group
    const bool active = d < n;

    f32x2 acc0 = {0.f, 0.f}, acc1 = {0.f, 0.f}, acc2 = {0.f, 0.f}, acc3 = {0.f, 0.f};
    float ssum = 0.f;
    float h0 = 0.f, h1 = 0.f, h2 = 0.f, h3 = 0.f, h4 = 0.f, h5 = 0.f, h6 = 0.f, h7 = 0.f;

    if (active) {
        const int p0 = offs[d], p1 = offs[d + 1];
        const float ad = a_d[d];
        const uint4* hW8 = (const uint4*)hWb;

        // 1-deep software pipeline: row/score of edge p prefetched during edge p-1
        int s_cur = (p0 < p1) ? esrc[p0] : 0;
        uint4 raw = hW8[(size_t)s_cur * 16 + l16];
        float as_cur = a_s[s_cur];
        for (int p = p0; p < p1; ++p) {
            const uint4 r = raw;
            const float e = leaky(as_cur + ad, 0.2f);
            const int pn = (p + 1 < p1) ? p + 1 : p;
            const int s_nxt = esrc[pn];
            raw = hW8[(size_t)s_nxt * 16 + l16];
            as_cur = a_s[s_nxt];

            const float ex = __expf(e);
            ssum += ex;
            const f32x2 exv = {ex, ex};
            f32x2 v;
            v.x = f_of_bf16(r.x & 0xffff); v.y = f_of_bf16(r.x >> 16);
            acc0 = __builtin_elementwise_fma(exv, v, acc0);
            v.x = f_of_bf16(r.y & 0xffff); v.y = f_of_bf16(r.y >> 16);
            acc1 = __builtin_elementwise_fma(exv, v, acc1);
            v.x = f_of_bf16(r.z & 0xffff); v.y = f_of_bf16(r.z >> 16);
            acc2 = __builtin_elementwise_fma(exv, v, acc2);
            v.x = f_of_bf16(r.w & 0xffff); v.y = f_of_bf16(r.w >> 16);
            acc3 = __builtin_elementwise_fma(exv, v, acc3);
        }

        const float inv = 1.f / (ssum + 1e-16f);
        const float4* b4p = (const float4*)bias;
        const float4 bb0 = b4p[l16 * 2], bb1 = b4p[l16 * 2 + 1];
        h0 = fmaf(acc0.x, inv, bb0.x); h1 = fmaf(acc0.y, inv, bb0.y);
        h2 = fmaf(acc1.x, inv, bb0.z); h3 = fmaf(acc1.y, inv, bb0.w);
        h4 = fmaf(acc2.x, inv, bb1.x); h5 = fmaf(acc2.y, inv, bb1.y);
        h6 = fmaf(acc3.x, inv, bb1.z); h7 = fmaf(acc3.y, inv, bb1.w);
        if (part != nullptr) {   // layers 0,1 feed the next GEMM; layer 2's hb is dead
            uint4 o;
            o.x = (unsigned)bf16_of(h0) | ((unsigned)bf16_of(h1) << 16);
            o.y = (unsigned)bf16_of(h2) | ((unsigned)bf16_of(h3) << 16);
            o.z = (unsigned)bf16_of(h4) | ((unsigned)bf16_of(h5) << 16);
            o.w = (unsigned)bf16_of(h6) | ((unsigned)bf16_of(h7) << 16);
            ((uint4*)hb)[(size_t)d * 16 + l16] = o;
        }
    }

    if (part != nullptr) {
        // ---- GraphNorm stats tail (colstat layout: tid holds cols l16*8+k) ----
        ss[tid][0] = active ? h0 : 0.f; sq[tid][0] = active ? h0 * h0 : 0.f;
        ss[tid][1] = active ? h1 : 0.f; sq[tid][1] = active ? h1 * h1 : 0.f;
        ss[tid][2] = active ? h2 : 0.f; sq[tid][2] = active ? h2 * h2 : 0.f;
        ss[tid][3] = active ? h3 : 0.f; sq[tid][3] = active ? h3 * h3 : 0.f;
        ss[tid][4] = active ? h4 : 0.f; sq[tid][4] = active ? h4 * h4 : 0.f;
        ss[tid][5] = active ? h5 : 0.f; sq[tid][5] = active ? h5 * h5 : 0.f;
        ss[tid][6] = active ? h6 : 0.f; sq[tid][6] = active ? h6 * h6 : 0.f;
        ss[tid][7] = active ? h7 : 0.f; sq[tid][7] = active ? h7 * h7 : 0.f;
        __syncthreads();
        if (tid < 128) {
            int c = tid >> 3, k = tid & 7;     // col = c*8 + k = tid
            float S = 0.f, Q = 0.f;
#pragma unroll
            for (int g = 0; g < 16; ++g) {
                S += ss[g * 16 + c][k];
                Q += sq[g * 16 + c][k];
            }
            float* pslot = part + (size_t)(blockIdx.x & (CSB - 1)) * 256;
            atomicAdd(&pslot[tid], S);
            atomicAdd(&pslot[128 + tid], Q);
        }
    } else if (pooled != nullptr) {
        // ---- global_add_pool tail: <=2 graphs per block (batch sorted) ----
        const int nb0 = blockIdx.x * 16;
        const int g0 = batch[nb0 < n ? nb0 : (n - 1)];
        const int g1 = batch[(nb0 + 15) < n ? (nb0 + 15) : (n - 1)];
        const bool isg0 = active && (batch[d] == g0);
        const bool isg1 = active && !isg0;
        ss[tid][0] = isg0 ? h0 : 0.f; sq[tid][0] = isg1 ? h0 : 0.f;
        ss[tid][1] = isg0 ? h1 : 0.f; sq[tid][1] = isg1 ? h1 : 0.f;
        ss[tid][2] = isg0 ? h2 : 0.f; sq[tid][2] = isg1 ? h2 : 0.f;
        ss[tid][3] = isg0 ? h3 : 0.f; sq[tid][3] = isg1 ? h3 : 0.f;
        ss[tid][4] = isg0 ? h4 : 0.f; sq[tid][4] = isg1 ? h4 : 0.f;
        ss[tid][5] = isg0 ? h5 : 0.f; sq[tid][5] = isg1 ? h5 : 0.f;
        ss[tid][6] = isg0 ? h6 : 0.f; sq[tid][6] = isg1 ? h6 : 0.f;
        ss[tid][7] = isg0 ? h7 : 0.f; sq[tid][7] = isg1 ? h7 : 0.f;
        __syncthreads();
        if (tid < 128) {
            int c = tid >> 3, k = tid & 7;     // col = tid
            float S = 0.f, Q = 0.f;
#pragma unroll
            for (int g = 0; g < 16; ++g) {
                S += ss[g * 16 + c][k];
                Q += sq[g * 16 + c][k];
            }
            float* slot = pooled + (size_t)(blockIdx.x & (PSL - 1)) * (GG * HD);
            atomicAdd(&slot[g0 * HD + tid], S);
            if (g1 != g0) atomicAdd(&slot[g1 * HD + tid], Q);
        }
    }
}

// ---------------- reduce partials + alpha/beta (separate launch = free visibility) --
__global__ __launch_bounds__(256) void k_colfin(const float* __restrict__ part,
                                                const float* __restrict__ w,
                                                const float* __restrict__ bb,
                                                const float* __restrict__ ms,
                                                float* __restrict__ alpha,
                                                float* __restrict__ beta, float inv_n) {
    int tid = threadIdx.x;
    float a0 = 0.f, a1 = 0.f, a2 = 0.f, a3 = 0.f;
    for (int b = 0; b < CSB; b += 4) {
        a0 += part[(b + 0) * 256 + tid];
        a1 += part[(b + 1) * 256 + tid];
        a2 += part[(b + 2) * 256 + tid];
        a3 += part[(b + 3) * 256 + tid];
    }
    __shared__ float fin[256];
    fin[tid] = (a0 + a1) + (a2 + a3);
    __syncthreads();
    if (tid < 128) {
        float mean = fin[tid] * inv_n;
        float ex2 = fin[128 + tid] * inv_n;
        float m2 = mean * ms[tid];
        float var = ex2 - 2.f * m2 * mean + m2 * m2;
        float a = w[tid] * rsqrtf(var + 1e-5f);
        alpha[tid] = a;
        beta[tid] = bb[tid] - m2 * a;
    }
}

// ---------------- final MLP (sums the PSL pooled partial slots) ----------------
__global__ __launch_bounds__(128) void k_mlp(const float* __restrict__ pooled,
                                             const float* __restrict__ W1,
                                             const float* __restrict__ b1,
                                             const float* __restrict__ W2,
                                             const float* __restrict__ b2,
                                             float* __restrict__ out) {
    __shared__ float pr[HD];
    __shared__ float zs[HD];
    int g = blockIdx.x, t = threadIdx.x;
    float pv = 0.f;
#pragma unroll
    for (int k = 0; k < PSL; ++k) pv += pooled[(k * GG + g) * HD + t];
    pr[t] = pv;
    __syncthreads();
    float acc = b1[t];
#pragma unroll 8
    for (int k = 0; k < HD; ++k) acc = fmaf(pr[k], W1[k * HD + t], acc);
    zs[t] = leaky(acc, 0.01f);
    __syncthreads();
    if (t < 64) {
        float a2 = b2[t];
#pragma unroll 8
        for (int k = 0; k < HD; ++k) a2 = fmaf(zs[k], W2[k * 64 + t], a2);
        out[g * 64 + t] = a2;
    }
}

extern "C" void kernel_launch(void* const* d_in, const int* in_sizes, int n_in,
                              void* d_out, int out_size, void* d_ws, size_t ws_size,
                              hipStream_t stream) {
    const float* x        = (const float*)d_in[0];
    const int*   ei       = (const int*)d_in[1];
    const int*   batch    = (const int*)d_in[2];
    const float* Ws       = (const float*)d_in[3];
    const float* att_src  = (const float*)d_in[4];
    const float* att_dst  = (const float*)d_in[5];
    const float* conv_bias= (const float*)d_in[6];
    const float* gn_w     = (const float*)d_in[7];
    const float* gn_b     = (const float*)d_in[8];
    const float* gn_ms    = (const float*)d_in[9];
    const float* W1       = (const float*)d_in[10];
    const float* b1       = (const float*)d_in[11];
    const float* W2       = (const float*)d_in[12];
    const float* b2       = (const float*)d_in[13];
    float* out = (float*)d_out;

    const int n = in_sizes[2];       // 100000
    const int e = in_sizes[1] / 2;   // 600000
    const int* src = ei;
    const int* dst = ei + e;
    const int nbk = (n + 511) >> 9;  // 512-node buckets (n <= 262144 for ebuf packing)

    char* ws = (char*)d_ws;
    unsigned short* hWb = (unsigned short*)ws;                    // n*128 bf16
    unsigned short* hb  = hWb + (size_t)n * HD;                   // n*128 bf16
    float* a_s    = (float*)(hb + (size_t)n * HD);                // n
    float* a_d    = a_s + n;                                      // n
    float* alpha  = a_d + n;                                      // 128
    float* beta   = alpha + HD;                                   // 128
    float* pooled = beta + HD;                                    // PSL*GG*128
    float* part   = pooled + PSL * GG * HD;                       // 2*CSB*256
    unsigned short* Wt = (unsigned short*)(part + 2 * CSB * 256); // 3*128*128
    int* offs     = (int*)(Wt + 3 * 16384);                       // n+1
    int* esrc     = offs + n + 1;                                 // e
    int* ebuf     = esrc + e;                                     // e
    int* bhist    = ebuf + e;                                     // 256*512
    int* bbase    = bhist + 256 * 512;                            // 514
    int* bcur     = bbase + 514;                                  // 513

    float* part0 = part;
    float* part1 = part + CSB * 256;

    // ---- init (blocks 0..511) + bcount histograms (blocks 512..767) ----
    k_initb<<<768, 256, 0, stream>>>(Ws, Wt, part, pooled, dst, bhist, e);
    // ---- CSR build: scan, partition ----
    k_bscan<<<1, 512, 0, stream>>>(bhist, bbase, bcur, offs, nbk, n, e);
    k_part<<<256, 256, 0, stream>>>(src, dst, bcur, ebuf, e);

    // ---- layer 0 GEMM fused with bscatter (bscatter hides under GEMM) ----
    k_gemm_a32_bsc<<<nbk + (n + 63) / 64, 256, 0, stream>>>(
        x, Wt, att_src, att_dst, hWb, a_s, a_d,
        ebuf, bbase, offs, esrc, nbk, n);

    // ---- GAT layers ----
    for (int l = 0; l < 3; ++l) {
        if (l > 0) {
            k_gemm_a16<<<(n + 63) / 64, 256, 0, stream>>>(
                hb, Wt + l * 16384, att_src + l * HD, att_dst + l * HD,
                alpha, beta, hWb, a_s, a_d, n);
        }
        if (l < 2) {
            float* lpart = (l == 0) ? part0 : part1;
            k_agg<<<(n + 15) / 16, 256, 0, stream>>>(
                hWb, offs, esrc, a_s, a_d, conv_bias + l * HD, hb,
                lpart, batch, nullptr, n);
            k_colfin<<<1, 256, 0, stream>>>(lpart, gn_w + l * HD, gn_b + l * HD,
                                            gn_ms + l * HD, alpha, beta, 1.0f / n);
        } else {
            k_agg<<<(n + 15) / 16, 256, 0, stream>>>(
                hWb, offs, esrc, a_s, a_d, conv_bias + l * HD, hb,
                nullptr, batch, pooled, n);
        }
    }

    // ---- MLP (sums pooled partial slots) ----
    k_mlp<<<GG, HD, 0, stream>>>(pooled, W1, b1, W2, b2, out);
}

// Round 9
// 313.404 us; speedup vs baseline: 4.5606x; 1.0161x over previous
//
#include <hip/hip_runtime.h>
#include <math.h>

#define HD 128
#define GG 64
#define CSB 256   // colstat partial slots (per layer)
#define PSL 8     // pooled partial slots
#define NHB 64    // bcount histogram slices

typedef __attribute__((ext_vector_type(8))) short short8;
typedef __attribute__((ext_vector_type(4))) float f32x4;
typedef __attribute__((ext_vector_type(2))) float f32x2;

__device__ __forceinline__ float leaky(float x, float s) { return x > 0.f ? x : s * x; }

__device__ __forceinline__ unsigned short bf16_of(float f) {
    union { float f; unsigned u; } v; v.f = f;
    unsigned r = v.u + 0x7fffu + ((v.u >> 16) & 1u);
    return (unsigned short)(r >> 16);
}
__device__ __forceinline__ float f_of_bf16(unsigned short u) {
    union { unsigned u; float f; } v; v.u = ((unsigned)u) << 16;
    return v.f;
}

// XOR-swizzled LDS addressing for the 128x128 bf16 W tile (16B chunks).
__device__ __forceinline__ int sw(int row, int chunk) {
    return row * 128 + ((chunk ^ (row & 15)) << 3);
}

// -------- init (blocks 0..511): W->Wt bf16 transposed + zero part/pooled
// -------- bcount (blocks 512..512+NHB-1): race-free per-block dst histograms -> bhist
__global__ __launch_bounds__(256) void k_initb(const float* __restrict__ Ws,
                                               unsigned short* __restrict__ Wt,
                                               float* __restrict__ part,
                                               float* __restrict__ pooled,
                                               const int* __restrict__ dst,
                                               int* __restrict__ bhist, int e) {
    const int tid = threadIdx.x;
    if (blockIdx.x >= 512) {
        __shared__ int lh[512];
        const int bi = blockIdx.x - 512;           // 0..NHB-1
        for (int t = tid; t < 512; t += 256) lh[t] = 0;
        __syncthreads();
        const int chunk = (e + NHB - 1) / NHB;
        const int i0 = bi * chunk;
        const int i1 = min(e, i0 + chunk);
        for (int i = i0 + tid; i < i1; i += 256) atomicAdd(&lh[dst[i] >> 9], 1);
        __syncthreads();
        for (int t = tid; t < 512; t += 256) bhist[bi * 512 + t] = lh[t];
        return;
    }
    int i = blockIdx.x * 256 + tid;               // 0..131071
    if (i < 3 * 16384) {
        int l = i >> 14, rem = i & 16383;
        int nn = rem >> 7, k = rem & 127;
        Wt[i] = bf16_of(Ws[l * 16384 + k * 128 + nn]);
    }
    if (i < 2 * CSB * 256) part[i] = 0.f;         // 131072
    if (i < PSL * GG * HD) pooled[i] = 0.f;       // 65536
}

// ================= bucketed CSR build =============
// Buckets of 512 nodes: bucket b = dst >> 9, local id = dst & 511.
// ebuf packs (local << 18) | src  (valid for n <= 262144).

__global__ void k_bscan(const int* __restrict__ bhist, int* __restrict__ bbase,
                        int* __restrict__ bcur, int* __restrict__ offs,
                        int nbk, int n, int e) {
    __shared__ int s[512];
    int t = threadIdx.x;
    int v = 0;
    if (t < nbk) {
        for (int b = 0; b < NHB; ++b) v += bhist[b * 512 + t];
    }
    s[t] = v;
    __syncthreads();
    for (int off = 1; off < 512; off <<= 1) {
        int u = (t >= off) ? s[t - off] : 0;
        __syncthreads();
        s[t] += u;
        __syncthreads();
    }
    if (t < nbk) { bbase[t] = s[t] - v; bcur[t] = s[t] - v; }
    if (t == 0) { bbase[nbk] = e; offs[n] = e; }
}

__global__ __launch_bounds__(256) void k_part(const int* __restrict__ src,
                                              const int* __restrict__ dst,
                                              int* __restrict__ bcur,
                                              int* __restrict__ ebuf, int e) {
    __shared__ int lh[512];
    __shared__ int lbase[512];
    const int tid = threadIdx.x;
    const int chunk = (e + gridDim.x - 1) / gridDim.x;
    const int i0 = blockIdx.x * chunk;
    const int i1 = min(e, i0 + chunk);
    for (int t = tid; t < 512; t += 256) lh[t] = 0;
    __syncthreads();
    for (int i = i0 + tid; i < i1; i += 256) atomicAdd(&lh[dst[i] >> 9], 1);
    __syncthreads();
    for (int t = tid; t < 512; t += 256) {
        int c = lh[t];
        lbase[t] = c ? atomicAdd(&bcur[t], c) : 0;
    }
    __syncthreads();
    for (int t = tid; t < 512; t += 256) lh[t] = 0;
    __syncthreads();
    for (int i = i0 + tid; i < i1; i += 256) {
        int d = dst[i];
        int b = d >> 9;
        int p = lbase[b] + atomicAdd(&lh[b], 1);
        ebuf[p] = ((d & 511) << 18) | src[i];
    }
}

// ===== fused: bscatter (blocks 0..nbk-1) + GEMM layer0 (rest), 512 threads =====
// 512-thread GEMM blocks cover 128 rows (8 waves x 16 rows, per-wave code
// identical to validated 256-thread form). LDS 32KB + 512thr -> up to 4 blk/CU
// = 32 waves/CU (vs 20); W-staging traffic and block count halve.
__global__ __launch_bounds__(512) void k_gemm_a32_bsc(
    const float* __restrict__ A, const unsigned short* __restrict__ Wt,
    const float* __restrict__ att_s, const float* __restrict__ att_d,
    unsigned short* __restrict__ hWb, float* __restrict__ a_s, float* __restrict__ a_d,
    const int* __restrict__ ebuf, const int* __restrict__ bbase,
    int* __restrict__ offs, int* __restrict__ esrc, int nbk, int n) {
    __shared__ unsigned short Bs[128 * 128];
    const int tid = threadIdx.x;

    if (blockIdx.x < nbk) {
        // ---------------- bscatter role (512 threads = 512 bucket slots) --------
        int* cnt = (int*)Bs;        // 512 ints
        int* sc  = cnt + 512;       // 512 ints
        int* pos = sc + 512;        // 512 ints (6KB total, < 32KB)
        const int b = blockIdx.x;
        const int nb0 = b << 9;
        const int e0 = bbase[b], e1 = bbase[b + 1];
        cnt[tid] = 0;
        __syncthreads();
        for (int i = e0 + tid; i < e1; i += 512) atomicAdd(&cnt[ebuf[i] >> 18], 1);
        __syncthreads();
        sc[tid] = cnt[tid];
        __syncthreads();
        for (int off = 1; off < 512; off <<= 1) {
            int u = (tid >= off) ? sc[tid - off] : 0;
            __syncthreads();
            sc[tid] += u;
            __syncthreads();
        }
        int myPos = e0 + sc[tid] - cnt[tid];
        pos[tid] = myPos;
        int node = nb0 + tid;
        if (node < n) offs[node] = myPos;
        __syncthreads();
        for (int i = e0 + tid; i < e1; i += 512) {
            int v = ebuf[i];
            int l = v >> 18;
            int p = atomicAdd(&pos[l], 1);
            esrc[p] = v & 0x3FFFF;
        }
        return;
    }

    // ---------------- GEMM role (round-1 per-wave form, 8 waves) ----------------
    const int base = (blockIdx.x - nbk) * 128;

    const uint4* Wt4 = (const uint4*)Wt;
    uint4* Bs4 = (uint4*)Bs;
#pragma unroll
    for (int j = 0; j < 4; ++j) {
        int flat = tid + j * 512;
        int col = flat >> 4, c8 = flat & 15;
        Bs4[(col << 4) + (c8 ^ (col & 15))] = Wt4[flat];
    }

    const int wave = tid >> 6, lane = tid & 63;
    const int m16 = lane & 15, quad = lane >> 4;

    short8 af[4];
    {
        int row = base + wave * 16 + m16;
        row = (row < n) ? row : (n - 1);
        const float4* ap = (const float4*)(A + (size_t)row * 128);
#pragma unroll
        for (int kk = 0; kk < 4; ++kk) {
            float4 v0 = ap[kk * 8 + quad * 2];
            float4 v1 = ap[kk * 8 + quad * 2 + 1];
            union { short8 s; unsigned u[4]; } P;
            P.u[0] = (unsigned)bf16_of(v0.x) | ((unsigned)bf16_of(v0.y) << 16);
            P.u[1] = (unsigned)bf16_of(v0.z) | ((unsigned)bf16_of(v0.w) << 16);
            P.u[2] = (unsigned)bf16_of(v1.x) | ((unsigned)bf16_of(v1.y) << 16);
            P.u[3] = (unsigned)bf16_of(v1.z) | ((unsigned)bf16_of(v1.w) << 16);
            af[kk] = P.s;
        }
    }
    __syncthreads();

    f32x4 acc[8];
#pragma unroll
    for (int ct = 0; ct < 8; ++ct) acc[ct] = (f32x4){0.f, 0.f, 0.f, 0.f};
#pragma unroll
    for (int kk = 0; kk < 4; ++kk) {
#pragma unroll
        for (int ct = 0; ct < 8; ++ct) {
            short8 bfr = *(const short8*)&Bs[sw(ct * 16 + m16, kk * 4 + quad)];
            acc[ct] = __builtin_amdgcn_mfma_f32_16x16x32_bf16(af[kk], bfr, acc[ct], 0, 0, 0);
        }
    }

#pragma unroll
    for (int reg = 0; reg < 4; ++reg) {
        int gr = base + wave * 16 + quad * 4 + reg;
        bool ok = gr < n;
        unsigned short* rowp = hWb + (size_t)gr * 128 + m16;
        float s = 0.f, dd = 0.f;
#pragma unroll
        for (int ct = 0; ct < 8; ++ct) {
            float v = acc[ct][reg];
            int col = ct * 16 + m16;
            if (ok) rowp[ct * 16] = bf16_of(v);
            s = fmaf(v, att_s[col], s);
            dd = fmaf(v, att_d[col], dd);
        }
#pragma unroll
        for (int off = 1; off < 16; off <<= 1) {
            s += __shfl_xor(s, off, 64);
            dd += __shfl_xor(dd, off, 64);
        }
        if (m16 == 0 && ok) { a_s[gr] = s; a_d[gr] = dd; }
    }
}

// ---- GEMM variant B: bf16 input + GraphNorm affine + leaky (layers 1,2) ----
__global__ __launch_bounds__(512) void k_gemm_a16(
    const unsigned short* __restrict__ Ab, const unsigned short* __restrict__ Wt,
    const float* __restrict__ att_s, const float* __restrict__ att_d,
    const float* __restrict__ alpha, const float* __restrict__ beta,
    unsigned short* __restrict__ hWb, float* __restrict__ a_s, float* __restrict__ a_d,
    int n) {
    __shared__ unsigned short Bs[128 * 128];
    const int tid = threadIdx.x;
    const int base = blockIdx.x * 128;

    const uint4* Wt4 = (const uint4*)Wt;
    uint4* Bs4 = (uint4*)Bs;
#pragma unroll
    for (int j = 0; j < 4; ++j) {
        int flat = tid + j * 512;
        int col = flat >> 4, c8 = flat & 15;
        Bs4[(col << 4) + (c8 ^ (col & 15))] = Wt4[flat];
    }

    const int wave = tid >> 6, lane = tid & 63;
    const int m16 = lane & 15, quad = lane >> 4;
    const float4* al4 = (const float4*)alpha;
    const float4* be4 = (const float4*)beta;

    short8 af[4];
    {
        int row = base + wave * 16 + m16;
        row = (row < n) ? row : (n - 1);
        const uint4* ap = (const uint4*)(Ab + (size_t)row * 128);
#pragma unroll
        for (int kk = 0; kk < 4; ++kk) {
            uint4 raw = ap[kk * 4 + quad];
            int c4 = kk * 8 + quad * 2;
            float4 a0 = al4[c4], a1 = al4[c4 + 1];
            float4 b0 = be4[c4], b1 = be4[c4 + 1];
            float f0 = leaky(fmaf(f_of_bf16(raw.x & 0xffff), a0.x, b0.x), 0.01f);
            float f1 = leaky(fmaf(f_of_bf16(raw.x >> 16),    a0.y, b0.y), 0.01f);
            float f2 = leaky(fmaf(f_of_bf16(raw.y & 0xffff), a0.z, b0.z), 0.01f);
            float f3 = leaky(fmaf(f_of_bf16(raw.y >> 16),    a0.w, b0.w), 0.01f);
            float f4 = leaky(fmaf(f_of_bf16(raw.z & 0xffff), a1.x, b1.x), 0.01f);
            float f5 = leaky(fmaf(f_of_bf16(raw.z >> 16),    a1.y, b1.y), 0.01f);
            float f6 = leaky(fmaf(f_of_bf16(raw.w & 0xffff), a1.z, b1.z), 0.01f);
            float f7 = leaky(fmaf(f_of_bf16(raw.w >> 16),    a1.w, b1.w), 0.01f);
            union { short8 s; unsigned u[4]; } P;
            P.u[0] = (unsigned)bf16_of(f0) | ((unsigned)bf16_of(f1) << 16);
            P.u[1] = (unsigned)bf16_of(f2) | ((unsigned)bf16_of(f3) << 16);
            P.u[2] = (unsigned)bf16_of(f4) | ((unsigned)bf16_of(f5) << 16);
            P.u[3] = (unsigned)bf16_of(f6) | ((unsigned)bf16_of(f7) << 16);
            af[kk] = P.s;
        }
    }
    __syncthreads();

    f32x4 acc[8];
#pragma unroll
    for (int ct = 0; ct < 8; ++ct) acc[ct] = (f32x4){0.f, 0.f, 0.f, 0.f};
#pragma unroll
    for (int kk = 0; kk < 4; ++kk) {
#pragma unroll
        for (int ct = 0; ct < 8; ++ct) {
            short8 bfr = *(const short8*)&Bs[sw(ct * 16 + m16, kk * 4 + quad)];
            acc[ct] = __builtin_amdgcn_mfma_f32_16x16x32_bf16(af[kk], bfr, acc[ct], 0, 0, 0);
        }
    }

#pragma unroll
    for (int reg = 0; reg < 4; ++reg) {
        int gr = base + wave * 16 + quad * 4 + reg;
        bool ok = gr < n;
        unsigned short* rowp = hWb + (size_t)gr * 128 + m16;
        float s = 0.f, dd = 0.f;
#pragma unroll
        for (int ct = 0; ct < 8; ++ct) {
            float v = acc[ct][reg];
            int col = ct * 16 + m16;
            if (ok) rowp[ct * 16] = bf16_of(v);
            s = fmaf(v, att_s[col], s);
            dd = fmaf(v, att_d[col], dd);
        }
#pragma unroll
        for (int off = 1; off < 16; off <<= 1) {
            s += __shfl_xor(s, off, 64);
            dd += __shfl_xor(dd, off, 64);
        }
        if (m16 == 0 && ok) { a_s[gr] = s; a_d[gr] = dd; }
    }
}

// ---------------- fused attention softmax + aggregation -------------------
// One 16-lane group per destination node. Tails (NO fences, NO device counters):
//   part != nullptr (layers 0,1): write bf16 h + GraphNorm stats block-reduce +
//     atomicAdd into part slot. alpha/beta computed by separate k_colfin launch.
//   pooled != nullptr (layer 2): NO h store (dead); block-reduce per-graph
//     partial sums (<=2 graphs per 16-node block, batch sorted) + atomicAdd
//     into one of PSL pooled slots.
__global__ __launch_bounds__(256) void k_agg(
    const unsigned short* __restrict__ hWb,
    const int* __restrict__ offs, const int* __restrict__ esrc,
    const float* __restrict__ a_s, const float* __restrict__ a_d,
    const float* __restrict__ bias, unsigned short* __restrict__ hb,
    float* __restrict__ part, const int* __restrict__ batch,
    float* __restrict__ pooled, int n) {
    __shared__ float ss[256][9];
    __shared__ float sq[256][9];
    const int tid = threadIdx.x;
    const int l16 = tid & 15;
    const int d = blockIdx.x * 16 + (tid >> 4);   // one node per 16-lane group
    const bool active = d < n;

    f32x2 acc0 = {0.f, 0.f}, acc1 = {0.f, 0.f}, acc2 = {0.f, 0.f}, acc3 = {0.f, 0.f};
    float ssum = 0.f;
    float h0 = 0.f, h1 = 0.f, h2 = 0.f, h3 = 0.f, h4 = 0.f, h5 = 0.f, h6 = 0.f, h7 = 0.f;

    if (active) {
        const int p0 = offs[d], p1 = offs[d + 1];
        const float ad = a_d[d];
        const uint4* hW8 = (const uint4*)hWb;

        // 1-deep software pipeline: row/score of edge p prefetched during edge p-1
        int s_cur = (p0 < p1) ? esrc[p0] : 0;
        uint4 raw = hW8[(size_t)s_cur * 16 + l16];
        float as_cur = a_s[s_cur];
        for (int p = p0; p < p1; ++p) {
            const uint4 r = raw;
            const float e = leaky(as_cur + ad, 0.2f);
            const int pn = (p + 1 < p1) ? p + 1 : p;
            const int s_nxt = esrc[pn];
            raw = hW8[(size_t)s_nxt * 16 + l16];
            as_cur = a_s[s_nxt];

            const float ex = __expf(e);
            ssum += ex;
            const f32x2 exv = {ex, ex};
            f32x2 v;
            v.x = f_of_bf16(r.x & 0xffff); v.y = f_of_bf16(r.x >> 16);
            acc0 = __builtin_elementwise_fma(exv, v, acc0);
            v.x = f_of_bf16(r.y & 0xffff); v.y = f_of_bf16(r.y >> 16);
            acc1 = __builtin_elementwise_fma(exv, v, acc1);
            v.x = f_of_bf16(r.z & 0xffff); v.y = f_of_bf16(r.z >> 16);
            acc2 = __builtin_elementwise_fma(exv, v, acc2);
            v.x = f_of_bf16(r.w & 0xffff); v.y = f_of_bf16(r.w >> 16);
            acc3 = __builtin_elementwise_fma(exv, v, acc3);
        }

        const float inv = 1.f / (ssum + 1e-16f);
        const float4* b4p = (const float4*)bias;
        const float4 bb0 = b4p[l16 * 2], bb1 = b4p[l16 * 2 + 1];
        h0 = fmaf(acc0.x, inv, bb0.x); h1 = fmaf(acc0.y, inv, bb0.y);
        h2 = fmaf(acc1.x, inv, bb0.z); h3 = fmaf(acc1.y, inv, bb0.w);
        h4 = fmaf(acc2.x, inv, bb1.x); h5 = fmaf(acc2.y, inv, bb1.y);
        h6 = fmaf(acc3.x, inv, bb1.z); h7 = fmaf(acc3.y, inv, bb1.w);
        if (part != nullptr) {   // layers 0,1 feed the next GEMM; layer 2's hb is dead
            uint4 o;
            o.x = (unsigned)bf16_of(h0) | ((unsigned)bf16_of(h1) << 16);
            o.y = (unsigned)bf16_of(h2) | ((unsigned)bf16_of(h3) << 16);
            o.z = (unsigned)bf16_of(h4) | ((unsigned)bf16_of(h5) << 16);
            o.w = (unsigned)bf16_of(h6) | ((unsigned)bf16_of(h7) << 16);
            ((uint4*)hb)[(size_t)d * 16 + l16] = o;
        }
    }

    if (part != nullptr) {
        // ---- GraphNorm stats tail (colstat layout: tid holds cols l16*8+k) ----
        ss[tid][0] = active ? h0 : 0.f; sq[tid][0] = active ? h0 * h0 : 0.f;
        ss[tid][1] = active ? h1 : 0.f; sq[tid][1] = active ? h1 * h1 : 0.f;
        ss[tid][2] = active ? h2 : 0.f; sq[tid][2] = active ? h2 * h2 : 0.f;
        ss[tid][3] = active ? h3 : 0.f; sq[tid][3] = active ? h3 * h3 : 0.f;
        ss[tid][4] = active ? h4 : 0.f; sq[tid][4] = active ? h4 * h4 : 0.f;
        ss[tid][5] = active ? h5 : 0.f; sq[tid][5] = active ? h5 * h5 : 0.f;
        ss[tid][6] = active ? h6 : 0.f; sq[tid][6] = active ? h6 * h6 : 0.f;
        ss[tid][7] = active ? h7 : 0.f; sq[tid][7] = active ? h7 * h7 : 0.f;
        __syncthreads();
        if (tid < 128) {
            int c = tid >> 3, k = tid & 7;     // col = c*8 + k = tid
            float S = 0.f, Q = 0.f;
#pragma unroll
            for (int g = 0; g < 16; ++g) {
                S += ss[g * 16 + c][k];
                Q += sq[g * 16 + c][k];
            }
            float* pslot = part + (size_t)(blockIdx.x & (CSB - 1)) * 256;
            atomicAdd(&pslot[tid], S);
            atomicAdd(&pslot[128 + tid], Q);
        }
    } else if (pooled != nullptr) {
        // ---- global_add_pool tail: <=2 graphs per block (batch sorted) ----
        const int nb0 = blockIdx.x * 16;
        const int g0 = batch[nb0 < n ? nb0 : (n - 1)];
        const int g1 = batch[(nb0 + 15) < n ? (nb0 + 15) : (n - 1)];
        const bool isg0 = active && (batch[d] == g0);
        const bool isg1 = active && !isg0;
        ss[tid][0] = isg0 ? h0 : 0.f; sq[tid][0] = isg1 ? h0 : 0.f;
        ss[tid][1] = isg0 ? h1 : 0.f; sq[tid][1] = isg1 ? h1 : 0.f;
        ss[tid][2] = isg0 ? h2 : 0.f; sq[tid][2] = isg1 ? h2 : 0.f;
        ss[tid][3] = isg0 ? h3 : 0.f; sq[tid][3] = isg1 ? h3 : 0.f;
        ss[tid][4] = isg0 ? h4 : 0.f; sq[tid][4] = isg1 ? h4 : 0.f;
        ss[tid][5] = isg0 ? h5 : 0.f; sq[tid][5] = isg1 ? h5 : 0.f;
        ss[tid][6] = isg0 ? h6 : 0.f; sq[tid][6] = isg1 ? h6 : 0.f;
        ss[tid][7] = isg0 ? h7 : 0.f; sq[tid][7] = isg1 ? h7 : 0.f;
        __syncthreads();
        if (tid < 128) {
            int c = tid >> 3, k = tid & 7;     // col = tid
            float S = 0.f, Q = 0.f;
#pragma unroll
            for (int g = 0; g < 16; ++g) {
                S += ss[g * 16 + c][k];
                Q += sq[g * 16 + c][k];
            }
            float* slot = pooled + (size_t)(blockIdx.x & (PSL - 1)) * (GG * HD);
            atomicAdd(&slot[g0 * HD + tid], S);
            if (g1 != g0) atomicAdd(&slot[g1 * HD + tid], Q);
        }
    }
}

// ---------------- reduce partials + alpha/beta (separate launch = free visibility) --
__global__ __launch_bounds__(256) void k_colfin(const float* __restrict__ part,
                                                const float* __restrict__ w,
                                                const float* __restrict__ bb,
                                                const float* __restrict__ ms,
                                                float* __restrict__ alpha,
                                                float* __restrict__ beta, float inv_n) {
    int tid = threadIdx.x;
    float a0 = 0.f, a1 = 0.f, a2 = 0.f, a3 = 0.f;
    for (int b = 0; b < CSB; b += 4) {
        a0 += part[(b + 0) * 256 + tid];
        a1 += part[(b + 1) * 256 + tid];
        a2 += part[(b + 2) * 256 + tid];
        a3 += part[(b + 3) * 256 + tid];
    }
    __shared__ float fin[256];
    fin[tid] = (a0 + a1) + (a2 + a3);
    __syncthreads();
    if (tid < 128) {
        float mean = fin[tid] * inv_n;
        float ex2 = fin[128 + tid] * inv_n;
        float m2 = mean * ms[tid];
        float var = ex2 - 2.f * m2 * mean + m2 * m2;
        float a = w[tid] * rsqrtf(var + 1e-5f);
        alpha[tid] = a;
        beta[tid] = bb[tid] - m2 * a;
    }
}

// ---------------- final MLP (sums the PSL pooled partial slots) ----------------
__global__ __launch_bounds__(128) void k_mlp(const float* __restrict__ pooled,
                                             const float* __restrict__ W1,
                                             const float* __restrict__ b1,
                                             const float* __restrict__ W2,
                                             const float* __restrict__ b2,
                                             float* __restrict__ out) {
    __shared__ float pr[HD];
    __shared__ float zs[HD];
    int g = blockIdx.x, t = threadIdx.x;
    float pv = 0.f;
#pragma unroll
    for (int k = 0; k < PSL; ++k) pv += pooled[(k * GG + g) * HD + t];
    pr[t] = pv;
    __syncthreads();
    float acc = b1[t];
#pragma unroll 8
    for (int k = 0; k < HD; ++k) acc = fmaf(pr[k], W1[k * HD + t], acc);
    zs[t] = leaky(acc, 0.01f);
    __syncthreads();
    if (t < 64) {
        float a2 = b2[t];
#pragma unroll 8
        for (int k = 0; k < HD; ++k) a2 = fmaf(zs[k], W2[k * 64 + t], a2);
        out[g * 64 + t] = a2;
    }
}

extern "C" void kernel_launch(void* const* d_in, const int* in_sizes, int n_in,
                              void* d_out, int out_size, void* d_ws, size_t ws_size,
                              hipStream_t stream) {
    const float* x        = (const float*)d_in[0];
    const int*   ei       = (const int*)d_in[1];
    const int*   batch    = (const int*)d_in[2];
    const float* Ws       = (const float*)d_in[3];
    const float* att_src  = (const float*)d_in[4];
    const float* att_dst  = (const float*)d_in[5];
    const float* conv_bias= (const float*)d_in[6];
    const float* gn_w     = (const float*)d_in[7];
    const float* gn_b     = (const float*)d_in[8];
    const float* gn_ms    = (const float*)d_in[9];
    const float* W1       = (const float*)d_in[10];
    const float* b1       = (const float*)d_in[11];
    const float* W2       = (const float*)d_in[12];
    const float* b2       = (const float*)d_in[13];
    float* out = (float*)d_out;

    const int n = in_sizes[2];       // 100000
    const int e = in_sizes[1] / 2;   // 600000
    const int* src = ei;
    const int* dst = ei + e;
    const int nbk = (n + 511) >> 9;  // 512-node buckets (n <= 262144 for ebuf packing)

    char* ws = (char*)d_ws;
    unsigned short* hWb = (unsigned short*)ws;                    // n*128 bf16
    unsigned short* hb  = hWb + (size_t)n * HD;                   // n*128 bf16
    float* a_s    = (float*)(hb + (size_t)n * HD);                // n
    float* a_d    = a_s + n;                                      // n
    float* alpha  = a_d + n;                                      // 128
    float* beta   = alpha + HD;                                   // 128
    float* pooled = beta + HD;                                    // PSL*GG*128
    float* part   = pooled + PSL * GG * HD;                       // 2*CSB*256
    unsigned short* Wt = (unsigned short*)(part + 2 * CSB * 256); // 3*128*128
    int* offs     = (int*)(Wt + 3 * 16384);                       // n+1
    int* esrc     = offs + n + 1;                                 // e
    int* ebuf     = esrc + e;                                     // e
    int* bhist    = ebuf + e;                                     // NHB*512
    int* bbase    = bhist + NHB * 512;                            // 514
    int* bcur     = bbase + 514;                                  // 513

    float* part0 = part;
    float* part1 = part + CSB * 256;

    // ---- init (blocks 0..511) + bcount histograms (blocks 512..512+NHB-1) ----
    k_initb<<<512 + NHB, 256, 0, stream>>>(Ws, Wt, part, pooled, dst, bhist, e);
    // ---- CSR build: scan, partition ----
    k_bscan<<<1, 512, 0, stream>>>(bhist, bbase, bcur, offs, nbk, n, e);
    k_part<<<256, 256, 0, stream>>>(src, dst, bcur, ebuf, e);

    // ---- layer 0 GEMM fused with bscatter (bscatter hides under GEMM) ----
    k_gemm_a32_bsc<<<nbk + (n + 127) / 128, 512, 0, stream>>>(
        x, Wt, att_src, att_dst, hWb, a_s, a_d,
        ebuf, bbase, offs, esrc, nbk, n);

    // ---- GAT layers ----
    for (int l = 0; l < 3; ++l) {
        if (l > 0) {
            k_gemm_a16<<<(n + 127) / 128, 512, 0, stream>>>(
                hb, Wt + l * 16384, att_src + l * HD, att_dst + l * HD,
                alpha, beta, hWb, a_s, a_d, n);
        }
        if (l < 2) {
            float* lpart = (l == 0) ? part0 : part1;
            k_agg<<<(n + 15) / 16, 256, 0, stream>>>(
                hWb, offs, esrc, a_s, a_d, conv_bias + l * HD, hb,
                lpart, batch, nullptr, n);
            k_colfin<<<1, 256, 0, stream>>>(lpart, gn_w + l * HD, gn_b + l * HD,
                                            gn_ms + l * HD, alpha, beta, 1.0f / n);
        } else {
            k_agg<<<(n + 15) / 16, 256, 0, stream>>>(
                hWb, offs, esrc, a_s, a_d, conv_bias + l * HD, hb,
                nullptr, batch, pooled, n);
        }
    }

    // ---- MLP (sums pooled partial slots) ----
    k_mlp<<<GG, HD, 0, stream>>>(pooled, W1, b1, W2, b2, out);
}